// Round 6
// baseline (287.203 us; speedup 1.0000x reference)
//
#include <hip/hip_runtime.h>
#include <hip/hip_bf16.h>

#define NTOK 8192
#define DIN  1024
#define HID  2048
#define OUTD 1024
#define NEXP 8
#define BM 256
#define BN 256
#define BK 32
#define MAXT (NTOK / BM + NEXP)   // 40 M-tiles max (256-row padding per expert)
#define SLOT (BM * BK)            // 8192 shorts = 16 KB per operand per slot
#define SLOT2 (2 * SLOT)          // A+B slot (32 KB)

typedef short short8 __attribute__((ext_vector_type(8)));
typedef float f32x4 __attribute__((ext_vector_type(4)));

static __device__ __forceinline__ unsigned short f2bf(float f) {
  union { __hip_bfloat16 b; unsigned short u; } cv;
  cv.b = __float2bfloat16(f);
  return cv.u;
}

static __device__ __forceinline__ void gload_lds16(const void* g, void* l) {
  __builtin_amdgcn_global_load_lds(
      (const __attribute__((address_space(1))) void*)g,
      (__attribute__((address_space(3))) void*)l, 16, 0, 0);
}

// ---------------- prep: W [E][R][C] fp32 -> WT [E][C][R] bf16 ----------------
__global__ __launch_bounds__(256) void transpose_convert_kernel(
    const float* __restrict__ W, unsigned short* __restrict__ WT, int R, int C) {
  __shared__ float tile[64][65];
  const int e = blockIdx.z;
  const int c0 = blockIdx.x * 64, r0 = blockIdx.y * 64;
  const int lr = threadIdx.x >> 4;    // 0..15
  const int fc = threadIdx.x & 15;    // float4 column
  const float* Wp = W + ((size_t)e * R + r0) * C + c0;
#pragma unroll
  for (int i = 0; i < 4; ++i) {
    int r = lr + i * 16;
    float4 v = *(const float4*)(Wp + (size_t)r * C + fc * 4);
    tile[r][fc * 4 + 0] = v.x; tile[r][fc * 4 + 1] = v.y;
    tile[r][fc * 4 + 2] = v.z; tile[r][fc * 4 + 3] = v.w;
  }
  __syncthreads();
  unsigned short* Op = WT + ((size_t)e * C + c0) * R + r0;
#pragma unroll
  for (int i = 0; i < 4; ++i) {
    int cc = lr + i * 16;             // output row = source col
    int rb = fc * 4;                  // 4 source rows
    ushort4 o = { f2bf(tile[rb + 0][cc]), f2bf(tile[rb + 1][cc]),
                  f2bf(tile[rb + 2][cc]), f2bf(tile[rb + 3][cc]) };
    *(ushort4*)(Op + (size_t)cc * R + rb) = o;
  }
}

// ---------------- fused: x fp32 -> bf16  +  router (fp32, NO atomics) ------
__global__ __launch_bounds__(256) void fused_router_kernel(
    const float* __restrict__ x, const float* __restrict__ Wr,
    const float* __restrict__ br, unsigned short* __restrict__ xb,
    float* __restrict__ probs_out, int* __restrict__ routes) {
  __shared__ float WrL[NEXP][DIN];   // transposed router weights, 32 KB
  const int tid = threadIdx.x;
#pragma unroll
  for (int rr = 0; rr < 4; ++rr) {
    int row = tid * 4 + rr;
    float4 w0 = *(const float4*)(Wr + (size_t)row * NEXP);
    float4 w1 = *(const float4*)(Wr + (size_t)row * NEXP + 4);
    WrL[0][row] = w0.x; WrL[1][row] = w0.y; WrL[2][row] = w0.z; WrL[3][row] = w0.w;
    WrL[4][row] = w1.x; WrL[5][row] = w1.y; WrL[6][row] = w1.z; WrL[7][row] = w1.w;
  }
  __syncthreads();

  const int lane = tid & 63;
  const int n = blockIdx.x * 4 + (tid >> 6);
  const float4* xr = (const float4*)(x + (size_t)n * DIN);
  ushort4* xo = (ushort4*)(xb + (size_t)n * DIN);
  float acc[NEXP];
#pragma unroll
  for (int e = 0; e < NEXP; ++e) acc[e] = 0.f;
#pragma unroll
  for (int j = 0; j < 4; ++j) {
    int idx = j * 64 + lane;            // coalesced: 64 consecutive float4
    float4 xv = xr[idx];
    ushort4 o = { f2bf(xv.x), f2bf(xv.y), f2bf(xv.z), f2bf(xv.w) };
    xo[idx] = o;
    int r0 = idx * 4;
#pragma unroll
    for (int e = 0; e < NEXP; ++e) {
      float4 wv = *(const float4*)&WrL[e][r0];
      acc[e] += xv.x * wv.x + xv.y * wv.y + xv.z * wv.z + xv.w * wv.w;
    }
  }
#pragma unroll
  for (int m = 1; m < 64; m <<= 1)
#pragma unroll
    for (int e = 0; e < NEXP; ++e) acc[e] += __shfl_xor(acc[e], m);

  if (lane == 0) {
    float lg[NEXP], p[NEXP];
    float mx = -1e30f;
#pragma unroll
    for (int e = 0; e < NEXP; ++e) { lg[e] = acc[e] + br[e]; mx = fmaxf(mx, lg[e]); }
    float s = 0.f;
#pragma unroll
    for (int e = 0; e < NEXP; ++e) { p[e] = expf(lg[e] - mx); s += p[e]; }
    float inv = 1.f / s;
    int best = 0; float bp = -1.f;
#pragma unroll
    for (int e = 0; e < NEXP; ++e) {
      p[e] *= inv;
      probs_out[(size_t)n * NEXP + e] = p[e];
      if (p[e] > bp) { bp = p[e]; best = e; }   // strict > : first-index tie-break
    }
    routes[n] = best;
  }
}

// ---------------- histogram + scan (single block, no atomics) ----------------
__global__ __launch_bounds__(256) void hist_scan_kernel(
    const int* __restrict__ routes, int* __restrict__ pad_off,
    int2* __restrict__ tile_table, float* __restrict__ counts_out) {
  __shared__ int wsum[4][NEXP];
  const int tid = threadIdx.x;
  const int lane = tid & 63, w = tid >> 6;
  int cnt[NEXP];
#pragma unroll
  for (int e = 0; e < NEXP; ++e) cnt[e] = 0;
#pragma unroll
  for (int j = 0; j < 8; ++j) {
    int4 r4 = ((const int4*)routes)[tid + 256 * j];
    int rr[4] = {r4.x, r4.y, r4.z, r4.w};
#pragma unroll
    for (int i = 0; i < 4; ++i)
#pragma unroll
      for (int e = 0; e < NEXP; ++e) cnt[e] += (rr[i] == e);  // no runtime idx -> regs
  }
#pragma unroll
  for (int m = 1; m < 64; m <<= 1)
#pragma unroll
    for (int e = 0; e < NEXP; ++e) cnt[e] += __shfl_xor(cnt[e], m);
  if (lane == 0)
#pragma unroll
    for (int e = 0; e < NEXP; ++e) wsum[w][e] = cnt[e];
  __syncthreads();
  if (tid == 0) {
    int off = 0, t = 0;
    for (int e = 0; e < NEXP; ++e) {
      int c = wsum[0][e] + wsum[1][e] + wsum[2][e] + wsum[3][e];
      pad_off[e] = off;
      counts_out[e] = (float)c;
      int tiles = (c + BM - 1) / BM;
      for (int i = 0; i < tiles; ++i) { tile_table[t] = make_int2(e, off + i * BM); ++t; }
      off += tiles * BM;
    }
    for (; t < MAXT; ++t) tile_table[t] = make_int2(-1, 0);
  }
}

// ---------------- build sorted token list (wave-aggregated atomics) ---------
__global__ void build_kernel(const int* __restrict__ routes,
                             const int* __restrict__ pad_off,
                             int* __restrict__ cursor,
                             int* __restrict__ sorted) {
  const int n = blockIdx.x * 256 + threadIdx.x;
  const int lane = threadIdx.x & 63;
  const int e = routes[n];
#pragma unroll
  for (int ex = 0; ex < NEXP; ++ex) {
    unsigned long long m = __ballot(e == ex);
    if (e == ex) {
      int leader = __ffsll(m) - 1;
      int rank = __popcll(m & ((1ull << lane) - 1ull));
      int b = 0;
      if (rank == 0) b = atomicAdd(&cursor[ex], (int)__popcll(m));
      b = __shfl(b, leader);
      sorted[pad_off[ex] + b + rank] = n;
    }
  }
}

// ---------------- grouped GEMM: 256x256 tile, 4-slot ring, counted vmcnt ----
// 8 waves (2M x 4N), per-wave 128x64 output. LDS = 4 slots x (A 16KB | B 16KB)
// = 128 KB (1 block/CU). Ring invariant: iteration t issues stage of tile t+3
// into slot (t+3)&3 (freed by iter t-1's end barrier); vmcnt(12) leaves only
// tiles t+1..t+3 outstanding => tile t complete per-wave; barrier makes it
// visible cross-wave. Loads stay in flight across barriers (never vmcnt(0)
// mid-loop). Chunk XOR swizzle c ^= (row&3)^((row>>2)&3) (involution) applied
// on BOTH the per-lane global source and the ds_read_b128 address (rule #21).
// A rows gathered via sorted[] (both modes); C rows scattered via sorted[].
// MODE 0: A = xb,   out = relu(acc+b1) -> bf16 hbuf[token][NDIM]
// MODE 1: A = hbuf, out = acc+b2       -> fp32 out[token][NDIM]
template <int KDIM, int MODE, int NB>
__global__ __launch_bounds__(512, 2) void gemm_moe(
    const unsigned short* __restrict__ A, const unsigned short* __restrict__ WT,
    const float* __restrict__ bias, const int* __restrict__ sorted,
    const int2* __restrict__ tile_table, void* __restrict__ Cout, int NDIM) {
  __shared__ short lds[4 * SLOT2];   // 128 KB

  // T1 bijective XCD swizzle (nwg % 8 == 0)
  const int nwg = NB * MAXT;
  const int bid = blockIdx.x;
  const int swz = (bid & 7) * (nwg >> 3) + (bid >> 3);
  const int2 tt = tile_table[swz / NB];
  if (tt.x < 0) return;
  const int expert = tt.x, mbase = tt.y;
  const int n0 = (swz % NB) * BN;
  const int tid = threadIdx.x, lane = tid & 63, w = tid >> 6;

  // ---- staging descriptors: 2 A-chunks + 2 B-chunks (16B) per thread/K-tile
  const short* asrc[2];
  const short* bsrc[2];
  int dsta[2], dstb[2];
#pragma unroll
  for (int i = 0; i < 2; ++i) {
    const int ci = i * 512 + tid;          // chunk id 0..1023 (row-major)
    const int row = ci >> 2, c = ci & 3;
    const int csw = (c ^ (row & 3) ^ ((row >> 2) & 3)) * 8;
    int tok = sorted[mbase + row];
    if (tok < 0) tok = 0;                   // pad: finite garbage, dropped at store
    asrc[i] = (const short*)A + (size_t)tok * KDIM + csw;
    bsrc[i] = (const short*)WT + ((size_t)expert * NDIM + n0 + row) * KDIM + csw;
    dsta[i] = ci * 8;                       // linear LDS dest (lane-contiguous)
    dstb[i] = SLOT + ci * 8;
  }

  // ---- fragment read offsets (within a slot, shorts)
  const int wm = w >> 2, wn = w & 3;        // wave grid 2 x 4
  const int fr = lane & 15, klo = lane >> 4;
  int aoff[8], boff[4];
#pragma unroll
  for (int m = 0; m < 8; ++m) {
    int r = wm * 128 + m * 16 + fr;
    aoff[m] = r * BK + ((klo ^ (r & 3) ^ ((r >> 2) & 3)) << 3);
  }
#pragma unroll
  for (int n = 0; n < 4; ++n) {
    int r = wn * 64 + n * 16 + fr;
    boff[n] = SLOT + r * BK + ((klo ^ (r & 3) ^ ((r >> 2) & 3)) << 3);
  }

  f32x4 acc[8][4];
#pragma unroll
  for (int m = 0; m < 8; ++m)
#pragma unroll
    for (int n = 0; n < 4; ++n) acc[m][n] = (f32x4){0.f, 0.f, 0.f, 0.f};

  constexpr int NT = KDIM / BK;
  // ring prologue: stage tiles 0..2
#pragma unroll
  for (int t = 0; t < 3; ++t) {
    const int sb = t * SLOT2, k0 = t * BK;
#pragma unroll
    for (int i = 0; i < 2; ++i) {
      gload_lds16(asrc[i] + k0, &lds[sb + dsta[i]]);
      gload_lds16(bsrc[i] + k0, &lds[sb + dstb[i]]);
    }
  }

  for (int t = 0; t < NT; ++t) {
    if (t + 3 < NT) {                       // stage tile t+3 (slot freed last iter)
      const int sb = ((t + 3) & 3) * SLOT2, k0 = (t + 3) * BK;
#pragma unroll
      for (int i = 0; i < 2; ++i) {
        gload_lds16(asrc[i] + k0, &lds[sb + dsta[i]]);
        gload_lds16(bsrc[i] + k0, &lds[sb + dstb[i]]);
      }
    }
    const int ahead = NT - 1 - t;           // tiles staged beyond t
    if (ahead >= 3)      asm volatile("s_waitcnt vmcnt(12)" ::: "memory");
    else if (ahead == 2) asm volatile("s_waitcnt vmcnt(8)" ::: "memory");
    else if (ahead == 1) asm volatile("s_waitcnt vmcnt(4)" ::: "memory");
    else                 asm volatile("s_waitcnt vmcnt(0)" ::: "memory");
    __syncthreads();                        // tile t fully visible to all waves

    const short* sl = &lds[(t & 3) * SLOT2];
    short8 a[8], b[4];
#pragma unroll
    for (int m = 0; m < 8; ++m) a[m] = *(const short8*)&sl[aoff[m]];
#pragma unroll
    for (int n = 0; n < 4; ++n) b[n] = *(const short8*)&sl[boff[n]];
    __builtin_amdgcn_s_setprio(1);
#pragma unroll
    for (int m = 0; m < 8; ++m)
#pragma unroll
      for (int n = 0; n < 4; ++n)
        acc[m][n] = __builtin_amdgcn_mfma_f32_16x16x32_bf16(a[m], b[n], acc[m][n], 0, 0, 0);
    __builtin_amdgcn_s_setprio(0);
    __syncthreads();                        // all reads of slot t done -> reusable
  }

  // ---- epilogue: scatter rows to token-indexed buffer
  const int fq = lane >> 4;
#pragma unroll
  for (int m = 0; m < 8; ++m) {
    int tok[4];
#pragma unroll
    for (int r = 0; r < 4; ++r)
      tok[r] = sorted[mbase + wm * 128 + m * 16 + fq * 4 + r];
#pragma unroll
    for (int n = 0; n < 4; ++n) {
      const int col = n0 + wn * 64 + n * 16 + fr;
      const float bv = bias[(size_t)expert * NDIM + col];
#pragma unroll
      for (int r = 0; r < 4; ++r) {
        if (tok[r] < 0) continue;           // pad row
        float v = acc[m][n][r] + bv;
        if (MODE == 0) {
          ((unsigned short*)Cout)[(size_t)tok[r] * NDIM + col] = f2bf(fmaxf(v, 0.f));
        } else {
          ((float*)Cout)[(size_t)tok[r] * NDIM + col] = v;
        }
      }
    }
  }
}

extern "C" void kernel_launch(void* const* d_in, const int* in_sizes, int n_in,
                              void* d_out, int out_size, void* d_ws, size_t ws_size,
                              hipStream_t stream) {
  const float* x  = (const float*)d_in[0];
  const float* Wr = (const float*)d_in[1];
  const float* br = (const float*)d_in[2];
  const float* W1 = (const float*)d_in[3];
  const float* b1 = (const float*)d_in[4];
  const float* W2 = (const float*)d_in[5];
  const float* b2 = (const float*)d_in[6];

  float* out_y      = (float*)d_out;                      // [N,O]
  float* out_probs  = out_y + (size_t)NTOK * OUTD;        // [N,E]
  float* out_counts = out_probs + (size_t)NTOK * NEXP;    // [E]

  char* ws = (char*)d_ws;
  unsigned short* xb   = (unsigned short*)(ws);                                  // 16 MB
  unsigned short* w1t  = (unsigned short*)(ws + 16777216ULL);                    // 32 MB
  unsigned short* w2t  = (unsigned short*)(ws + 50331648ULL);                    // 32 MB
  unsigned short* hbuf = (unsigned short*)(ws + 83886080ULL);                    // 32 MB (token-indexed)
  char* p = ws + 117440512ULL;
  int* routes   = (int*)p; p += 32768;
  int* sorted   = (int*)p; p += (NTOK + NEXP * BM) * 4;   // 40960 B
  int* cursor   = (int*)p; p += 256;
  int* pad_off  = (int*)p; p += 256;
  int2* tt      = (int2*)p;

  hipMemsetAsync(sorted, 0xFF, (NTOK + NEXP * BM) * sizeof(int), stream);
  hipMemsetAsync(cursor, 0, 256, stream);

  transpose_convert_kernel<<<dim3(HID / 64, DIN / 64, NEXP), 256, 0, stream>>>(W1, w1t, DIN, HID);
  transpose_convert_kernel<<<dim3(OUTD / 64, HID / 64, NEXP), 256, 0, stream>>>(W2, w2t, HID, OUTD);
  fused_router_kernel<<<NTOK / 4, 256, 0, stream>>>(x, Wr, br, xb, out_probs, routes);
  hist_scan_kernel<<<1, 256, 0, stream>>>(routes, pad_off, tt, out_counts);
  build_kernel<<<NTOK / 256, 256, 0, stream>>>(routes, pad_off, cursor, sorted);
  gemm_moe<DIN, 0, HID / BN><<<(HID / BN) * MAXT, 512, 0, stream>>>(
      xb, w1t, b1, sorted, tt, hbuf, HID);
  gemm_moe<HID, 1, OUTD / BN><<<(OUTD / BN) * MAXT, 512, 0, stream>>>(
      hbuf, w2t, b2, sorted, tt, out_y, OUTD);
}

// Round 7
// 259.068 us; speedup vs baseline: 1.1086x; 1.1086x over previous
//
#include <hip/hip_runtime.h>
#include <hip/hip_bf16.h>

#define NTOK 8192
#define DIN  1024
#define HID  2048
#define OUTD 1024
#define NEXP 8
#define BM 256
#define BK 32
#define MAXT (NTOK / BM + NEXP)   // 40 M-tiles max (256-row padding per expert)

typedef short short8 __attribute__((ext_vector_type(8)));
typedef float f32x4 __attribute__((ext_vector_type(4)));

static __device__ __forceinline__ unsigned short f2bf(float f) {
  union { __hip_bfloat16 b; unsigned short u; } cv;
  cv.b = __float2bfloat16(f);
  return cv.u;
}

static __device__ __forceinline__ void gload_lds16(const void* g, void* l) {
  __builtin_amdgcn_global_load_lds(
      (const __attribute__((address_space(1))) void*)g,
      (__attribute__((address_space(3))) void*)l, 16, 0, 0);
}

template <int N>
static __device__ __forceinline__ void wait_vm() {
  if constexpr (N == 0)       asm volatile("s_waitcnt vmcnt(0)" ::: "memory");
  else if constexpr (N == 3)  asm volatile("s_waitcnt vmcnt(3)" ::: "memory");
  else if constexpr (N == 4)  asm volatile("s_waitcnt vmcnt(4)" ::: "memory");
  else if constexpr (N == 6)  asm volatile("s_waitcnt vmcnt(6)" ::: "memory");
  else if constexpr (N == 8)  asm volatile("s_waitcnt vmcnt(8)" ::: "memory");
  else if constexpr (N == 9)  asm volatile("s_waitcnt vmcnt(9)" ::: "memory");
  else if constexpr (N == 12) asm volatile("s_waitcnt vmcnt(12)" ::: "memory");
}

// ---------------- prep: W [E][R][C] fp32 -> WT [E][C][R] bf16 ----------------
__global__ __launch_bounds__(256) void transpose_convert_kernel(
    const float* __restrict__ W, unsigned short* __restrict__ WT, int R, int C) {
  __shared__ float tile[64][65];
  const int e = blockIdx.z;
  const int c0 = blockIdx.x * 64, r0 = blockIdx.y * 64;
  const int lr = threadIdx.x >> 4;    // 0..15
  const int fc = threadIdx.x & 15;    // float4 column
  const float* Wp = W + ((size_t)e * R + r0) * C + c0;
#pragma unroll
  for (int i = 0; i < 4; ++i) {
    int r = lr + i * 16;
    float4 v = *(const float4*)(Wp + (size_t)r * C + fc * 4);
    tile[r][fc * 4 + 0] = v.x; tile[r][fc * 4 + 1] = v.y;
    tile[r][fc * 4 + 2] = v.z; tile[r][fc * 4 + 3] = v.w;
  }
  __syncthreads();
  unsigned short* Op = WT + ((size_t)e * C + c0) * R + r0;
#pragma unroll
  for (int i = 0; i < 4; ++i) {
    int cc = lr + i * 16;             // output row = source col
    int rb = fc * 4;                  // 4 source rows
    ushort4 o = { f2bf(tile[rb + 0][cc]), f2bf(tile[rb + 1][cc]),
                  f2bf(tile[rb + 2][cc]), f2bf(tile[rb + 3][cc]) };
    *(ushort4*)(Op + (size_t)cc * R + rb) = o;
  }
}

// ---------------- fused: x fp32 -> bf16  +  router (fp32, NO atomics) ------
__global__ __launch_bounds__(256) void fused_router_kernel(
    const float* __restrict__ x, const float* __restrict__ Wr,
    const float* __restrict__ br, unsigned short* __restrict__ xb,
    float* __restrict__ probs_out, int* __restrict__ routes) {
  __shared__ float WrL[NEXP][DIN];   // transposed router weights, 32 KB
  const int tid = threadIdx.x;
#pragma unroll
  for (int rr = 0; rr < 4; ++rr) {
    int row = tid * 4 + rr;
    float4 w0 = *(const float4*)(Wr + (size_t)row * NEXP);
    float4 w1 = *(const float4*)(Wr + (size_t)row * NEXP + 4);
    WrL[0][row] = w0.x; WrL[1][row] = w0.y; WrL[2][row] = w0.z; WrL[3][row] = w0.w;
    WrL[4][row] = w1.x; WrL[5][row] = w1.y; WrL[6][row] = w1.z; WrL[7][row] = w1.w;
  }
  __syncthreads();

  const int lane = tid & 63;
  const int n = blockIdx.x * 4 + (tid >> 6);
  const float4* xr = (const float4*)(x + (size_t)n * DIN);
  ushort4* xo = (ushort4*)(xb + (size_t)n * DIN);
  float acc[NEXP];
#pragma unroll
  for (int e = 0; e < NEXP; ++e) acc[e] = 0.f;
#pragma unroll
  for (int j = 0; j < 4; ++j) {
    int idx = j * 64 + lane;            // coalesced: 64 consecutive float4
    float4 xv = xr[idx];
    ushort4 o = { f2bf(xv.x), f2bf(xv.y), f2bf(xv.z), f2bf(xv.w) };
    xo[idx] = o;
    int r0 = idx * 4;
#pragma unroll
    for (int e = 0; e < NEXP; ++e) {
      float4 wv = *(const float4*)&WrL[e][r0];
      acc[e] += xv.x * wv.x + xv.y * wv.y + xv.z * wv.z + xv.w * wv.w;
    }
  }
#pragma unroll
  for (int m = 1; m < 64; m <<= 1)
#pragma unroll
    for (int e = 0; e < NEXP; ++e) acc[e] += __shfl_xor(acc[e], m);

  if (lane == 0) {
    float lg[NEXP], p[NEXP];
    float mx = -1e30f;
#pragma unroll
    for (int e = 0; e < NEXP; ++e) { lg[e] = acc[e] + br[e]; mx = fmaxf(mx, lg[e]); }
    float s = 0.f;
#pragma unroll
    for (int e = 0; e < NEXP; ++e) { p[e] = expf(lg[e] - mx); s += p[e]; }
    float inv = 1.f / s;
    int best = 0; float bp = -1.f;
#pragma unroll
    for (int e = 0; e < NEXP; ++e) {
      p[e] *= inv;
      probs_out[(size_t)n * NEXP + e] = p[e];
      if (p[e] > bp) { bp = p[e]; best = e; }   // strict > : first-index tie-break
    }
    routes[n] = best;
  }
}

// ---------------- histogram + scan (single block, no atomics) ----------------
__global__ __launch_bounds__(256) void hist_scan_kernel(
    const int* __restrict__ routes, int* __restrict__ pad_off,
    int2* __restrict__ tile_table, float* __restrict__ counts_out) {
  __shared__ int wsum[4][NEXP];
  const int tid = threadIdx.x;
  const int lane = tid & 63, w = tid >> 6;
  int cnt[NEXP];
#pragma unroll
  for (int e = 0; e < NEXP; ++e) cnt[e] = 0;
#pragma unroll
  for (int j = 0; j < 8; ++j) {
    int4 r4 = ((const int4*)routes)[tid + 256 * j];
    int rr[4] = {r4.x, r4.y, r4.z, r4.w};
#pragma unroll
    for (int i = 0; i < 4; ++i)
#pragma unroll
      for (int e = 0; e < NEXP; ++e) cnt[e] += (rr[i] == e);  // no runtime idx -> regs
  }
#pragma unroll
  for (int m = 1; m < 64; m <<= 1)
#pragma unroll
    for (int e = 0; e < NEXP; ++e) cnt[e] += __shfl_xor(cnt[e], m);
  if (lane == 0)
#pragma unroll
    for (int e = 0; e < NEXP; ++e) wsum[w][e] = cnt[e];
  __syncthreads();
  if (tid == 0) {
    int off = 0, t = 0;
    for (int e = 0; e < NEXP; ++e) {
      int c = wsum[0][e] + wsum[1][e] + wsum[2][e] + wsum[3][e];
      pad_off[e] = off;
      counts_out[e] = (float)c;
      int tiles = (c + BM - 1) / BM;
      for (int i = 0; i < tiles; ++i) { tile_table[t] = make_int2(e, off + i * BM); ++t; }
      off += tiles * BM;
    }
    for (; t < MAXT; ++t) tile_table[t] = make_int2(-1, 0);
  }
}

// ---------------- build sorted token list (wave-aggregated atomics) ---------
__global__ void build_kernel(const int* __restrict__ routes,
                             const int* __restrict__ pad_off,
                             int* __restrict__ cursor,
                             int* __restrict__ sorted) {
  const int n = blockIdx.x * 256 + threadIdx.x;
  const int lane = threadIdx.x & 63;
  const int e = routes[n];
#pragma unroll
  for (int ex = 0; ex < NEXP; ++ex) {
    unsigned long long m = __ballot(e == ex);
    if (e == ex) {
      int leader = __ffsll(m) - 1;
      int rank = __popcll(m & ((1ull << lane) - 1ull));
      int b = 0;
      if (rank == 0) b = atomicAdd(&cursor[ex], (int)__popcll(m));
      b = __shfl(b, leader);
      sorted[pad_off[ex] + b + rank] = n;
    }
  }
}

// ---------------- grouped GEMM: 256xBN_ tile, 4-slot ring, counted vmcnt ----
// 8 waves (2M x 4N), per-wave 128 x BN_/4 output. RAW s_barrier (no vmcnt
// drain!) + counted vmcnt keeps loads in flight across barriers:
// iter t: stage tile t+3 into slot (t+3)&3 (freed by iter t-1's end barrier);
// wait_vm<3*CPT> leaves only tiles t+1..t+3 outstanding => tile t complete
// per-wave; s_barrier makes it complete for ALL waves (each waited first).
// Chunk XOR swizzle c ^= (row&3)^((row>>2)&3) (involution) applied on BOTH
// the per-lane global source and the ds_read_b128 address (rule #21).
// MODE 0: A = xb,   out = relu(acc+b1) -> bf16 hbuf[token][NDIM]
// MODE 1: A = hbuf, out = acc+b2       -> fp32 out[token][NDIM]
template <int KDIM, int MODE, int BN_, int NB>
__global__ __launch_bounds__(512, 2) void gemm_moe(
    const unsigned short* __restrict__ A, const unsigned short* __restrict__ WT,
    const float* __restrict__ bias, const int* __restrict__ sorted,
    const int2* __restrict__ tile_table, void* __restrict__ Cout, int NDIM) {
  constexpr int SLOT_A = BM * BK;            // 8192 shorts
  constexpr int SLOT_B = BN_ * BK;
  constexpr int SLOTT = SLOT_A + SLOT_B;
  constexpr int CPT = (BM + BN_) * 4 / 512;  // 16B chunks per thread per tile
  constexpr int WN = BN_ / 4;                // wave N extent
  constexpr int NF = WN / 16;                // N fragments per wave
  __shared__ short lds[4 * SLOTT];

  // T1 bijective XCD swizzle (nwg % 8 == 0)
  const int nwg = NB * MAXT;
  const int bid = blockIdx.x;
  const int swz = (bid & 7) * (nwg >> 3) + (bid >> 3);
  const int2 tt = tile_table[swz / NB];
  if (tt.x < 0) return;
  const int expert = tt.x, mbase = tt.y;
  const int n0 = (swz % NB) * BN_;
  const int tid = threadIdx.x, lane = tid & 63, w = tid >> 6;

  // ---- staging descriptors: CPT 16B-chunks per thread per K-tile
  const short* src[CPT];
  int dst[CPT];
#pragma unroll
  for (int i = 0; i < CPT; ++i) {
    const int ci = i * 512 + tid;           // global chunk id (A then B)
    if (i < (BM * 4) / 512) {               // A chunk (compile-time per i)
      const int row = ci >> 2, c = ci & 3;
      const int csw = (c ^ (row & 3) ^ ((row >> 2) & 3)) * 8;
      int tok = sorted[mbase + row];
      if (tok < 0) tok = 0;                 // pad: finite garbage, dropped at store
      src[i] = (const short*)A + (size_t)tok * KDIM + csw;
      dst[i] = ci * 8;                      // linear LDS dest (lane-contiguous)
    } else {                                // B chunk
      const int bc = ci - BM * 4;
      const int row = bc >> 2, c = bc & 3;
      const int csw = (c ^ (row & 3) ^ ((row >> 2) & 3)) * 8;
      src[i] = (const short*)WT + ((size_t)expert * NDIM + n0 + row) * KDIM + csw;
      dst[i] = SLOT_A + bc * 8;
    }
  }

  // ---- fragment read offsets (within a slot, shorts)
  const int wm = w >> 2, wn = w & 3;        // wave grid 2 x 4
  const int fr = lane & 15, klo = lane >> 4;
  int aoff[8], boff[NF];
#pragma unroll
  for (int m = 0; m < 8; ++m) {
    int r = wm * 128 + m * 16 + fr;
    aoff[m] = r * BK + ((klo ^ (r & 3) ^ ((r >> 2) & 3)) << 3);
  }
#pragma unroll
  for (int n = 0; n < NF; ++n) {
    int r = wn * WN + n * 16 + fr;
    boff[n] = SLOT_A + r * BK + ((klo ^ (r & 3) ^ ((r >> 2) & 3)) << 3);
  }

  f32x4 acc[8][NF];
#pragma unroll
  for (int m = 0; m < 8; ++m)
#pragma unroll
    for (int n = 0; n < NF; ++n) acc[m][n] = (f32x4){0.f, 0.f, 0.f, 0.f};

  constexpr int NT = KDIM / BK;
  // ring prologue: stage tiles 0..2
#pragma unroll
  for (int t = 0; t < 3; ++t) {
    const int sb = t * SLOTT, k0 = t * BK;
#pragma unroll
    for (int i = 0; i < CPT; ++i) gload_lds16(src[i] + k0, &lds[sb + dst[i]]);
  }

  for (int t = 0; t < NT; ++t) {
    if (t + 3 < NT) {                       // stage tile t+3 (slot freed last iter)
      const int sb = ((t + 3) & 3) * SLOTT, k0 = (t + 3) * BK;
#pragma unroll
      for (int i = 0; i < CPT; ++i) gload_lds16(src[i] + k0, &lds[sb + dst[i]]);
    }
    const int ahead = NT - 1 - t;           // tiles staged beyond t
    if (ahead >= 3)      wait_vm<3 * CPT>();
    else if (ahead == 2) wait_vm<2 * CPT>();
    else if (ahead == 1) wait_vm<CPT>();
    else                 wait_vm<0>();
    __builtin_amdgcn_s_barrier();           // RAW barrier: no vmcnt drain
    __builtin_amdgcn_sched_barrier(0);      // keep ds_reads below the barrier

    const short* sl = &lds[(t & 3) * SLOTT];
    short8 a[8], b[NF];
#pragma unroll
    for (int m = 0; m < 8; ++m) a[m] = *(const short8*)&sl[aoff[m]];
#pragma unroll
    for (int n = 0; n < NF; ++n) b[n] = *(const short8*)&sl[boff[n]];
    __builtin_amdgcn_s_setprio(1);
#pragma unroll
    for (int m = 0; m < 8; ++m)
#pragma unroll
      for (int n = 0; n < NF; ++n)
        acc[m][n] = __builtin_amdgcn_mfma_f32_16x16x32_bf16(a[m], b[n], acc[m][n], 0, 0, 0);
    __builtin_amdgcn_s_setprio(0);
    __builtin_amdgcn_sched_barrier(0);      // MFMA consumed LDS reads above
    __builtin_amdgcn_s_barrier();           // slot t free for reuse next iter
    __builtin_amdgcn_sched_barrier(0);
  }

  // ---- epilogue: scatter rows to token-indexed buffer
  const int fq = lane >> 4;
#pragma unroll
  for (int m = 0; m < 8; ++m) {
    int tok[4];
#pragma unroll
    for (int r = 0; r < 4; ++r)
      tok[r] = sorted[mbase + wm * 128 + m * 16 + fq * 4 + r];
#pragma unroll
    for (int n = 0; n < NF; ++n) {
      const int col = n0 + wn * WN + n * 16 + fr;
      const float bv = bias[(size_t)expert * NDIM + col];
#pragma unroll
      for (int r = 0; r < 4; ++r) {
        if (tok[r] < 0) continue;           // pad row
        float v = acc[m][n][r] + bv;
        if (MODE == 0) {
          ((unsigned short*)Cout)[(size_t)tok[r] * NDIM + col] = f2bf(fmaxf(v, 0.f));
        } else {
          ((float*)Cout)[(size_t)tok[r] * NDIM + col] = v;
        }
      }
    }
  }
}

extern "C" void kernel_launch(void* const* d_in, const int* in_sizes, int n_in,
                              void* d_out, int out_size, void* d_ws, size_t ws_size,
                              hipStream_t stream) {
  const float* x  = (const float*)d_in[0];
  const float* Wr = (const float*)d_in[1];
  const float* br = (const float*)d_in[2];
  const float* W1 = (const float*)d_in[3];
  const float* b1 = (const float*)d_in[4];
  const float* W2 = (const float*)d_in[5];
  const float* b2 = (const float*)d_in[6];

  float* out_y      = (float*)d_out;                      // [N,O]
  float* out_probs  = out_y + (size_t)NTOK * OUTD;        // [N,E]
  float* out_counts = out_probs + (size_t)NTOK * NEXP;    // [E]

  char* ws = (char*)d_ws;
  unsigned short* xb   = (unsigned short*)(ws);                                  // 16 MB
  unsigned short* w1t  = (unsigned short*)(ws + 16777216ULL);                    // 32 MB
  unsigned short* w2t  = (unsigned short*)(ws + 50331648ULL);                    // 32 MB
  unsigned short* hbuf = (unsigned short*)(ws + 83886080ULL);                    // 32 MB (token-indexed)
  char* p = ws + 117440512ULL;
  int* routes   = (int*)p; p += 32768;
  int* sorted   = (int*)p; p += (NTOK + NEXP * BM) * 4;   // 40960 B
  int* cursor   = (int*)p; p += 256;
  int* pad_off  = (int*)p; p += 256;
  int2* tt      = (int2*)p;

  hipMemsetAsync(sorted, 0xFF, (NTOK + NEXP * BM) * sizeof(int), stream);
  hipMemsetAsync(cursor, 0, 256, stream);

  transpose_convert_kernel<<<dim3(HID / 64, DIN / 64, NEXP), 256, 0, stream>>>(W1, w1t, DIN, HID);
  transpose_convert_kernel<<<dim3(OUTD / 64, HID / 64, NEXP), 256, 0, stream>>>(W2, w2t, HID, OUTD);
  fused_router_kernel<<<NTOK / 4, 256, 0, stream>>>(x, Wr, br, xb, out_probs, routes);
  hist_scan_kernel<<<1, 256, 0, stream>>>(routes, pad_off, tt, out_counts);
  build_kernel<<<NTOK / 256, 256, 0, stream>>>(routes, pad_off, cursor, sorted);
  gemm_moe<DIN, 0, 256, HID / 256><<<(HID / 256) * MAXT, 512, 0, stream>>>(
      xb, w1t, b1, sorted, tt, hbuf, HID);
  gemm_moe<HID, 1, 128, OUTD / 128><<<(OUTD / 128) * MAXT, 512, 0, stream>>>(
      hbuf, w2t, b2, sorted, tt, out_y, OUTD);
}

// Round 8
// 244.279 us; speedup vs baseline: 1.1757x; 1.0605x over previous
//
#include <hip/hip_runtime.h>
#include <hip/hip_bf16.h>

#define NTOK 8192
#define DIN  1024
#define HID  2048
#define OUTD 1024
#define NEXP 8
#define BM 256
#define BK 32
#define MAXT (NTOK / BM + NEXP)   // 40 M-tiles max (256-row padding per expert)

typedef short short8 __attribute__((ext_vector_type(8)));
typedef float f32x4 __attribute__((ext_vector_type(4)));

static __device__ __forceinline__ unsigned short f2bf(float f) {
  union { __hip_bfloat16 b; unsigned short u; } cv;
  cv.b = __float2bfloat16(f);
  return cv.u;
}

static __device__ __forceinline__ void gload_lds16(const void* g, void* l) {
  __builtin_amdgcn_global_load_lds(
      (const __attribute__((address_space(1))) void*)g,
      (__attribute__((address_space(3))) void*)l, 16, 0, 0);
}

template <int N>
static __device__ __forceinline__ void wait_vm() {
  if constexpr (N == 0)      asm volatile("s_waitcnt vmcnt(0)" ::: "memory");
  else if constexpr (N == 3) asm volatile("s_waitcnt vmcnt(3)" ::: "memory");
  else if constexpr (N == 4) asm volatile("s_waitcnt vmcnt(4)" ::: "memory");
  else if constexpr (N == 6) asm volatile("s_waitcnt vmcnt(6)" ::: "memory");
  else if constexpr (N == 8) asm volatile("s_waitcnt vmcnt(8)" ::: "memory");
}

template <int N>
static __device__ __forceinline__ void wait_lgkm() {
  if constexpr (N == 0)       asm volatile("s_waitcnt lgkmcnt(0)" ::: "memory");
  else if constexpr (N == 8)  asm volatile("s_waitcnt lgkmcnt(8)" ::: "memory");
  else if constexpr (N == 10) asm volatile("s_waitcnt lgkmcnt(10)" ::: "memory");
  else if constexpr (N == 12) asm volatile("s_waitcnt lgkmcnt(12)" ::: "memory");
}

// ---------------- prep: W [E][R][C] fp32 -> WT [E][C][R] bf16 ----------------
__global__ __launch_bounds__(256) void transpose_convert_kernel(
    const float* __restrict__ W, unsigned short* __restrict__ WT, int R, int C) {
  __shared__ float tile[64][65];
  const int e = blockIdx.z;
  const int c0 = blockIdx.x * 64, r0 = blockIdx.y * 64;
  const int lr = threadIdx.x >> 4;    // 0..15
  const int fc = threadIdx.x & 15;    // float4 column
  const float* Wp = W + ((size_t)e * R + r0) * C + c0;
#pragma unroll
  for (int i = 0; i < 4; ++i) {
    int r = lr + i * 16;
    float4 v = *(const float4*)(Wp + (size_t)r * C + fc * 4);
    tile[r][fc * 4 + 0] = v.x; tile[r][fc * 4 + 1] = v.y;
    tile[r][fc * 4 + 2] = v.z; tile[r][fc * 4 + 3] = v.w;
  }
  __syncthreads();
  unsigned short* Op = WT + ((size_t)e * C + c0) * R + r0;
#pragma unroll
  for (int i = 0; i < 4; ++i) {
    int cc = lr + i * 16;             // output row = source col
    int rb = fc * 4;                  // 4 source rows
    ushort4 o = { f2bf(tile[rb + 0][cc]), f2bf(tile[rb + 1][cc]),
                  f2bf(tile[rb + 2][cc]), f2bf(tile[rb + 3][cc]) };
    *(ushort4*)(Op + (size_t)cc * R + rb) = o;
  }
}

// ---------------- fused: x fp32 -> bf16  +  router (fp32, NO atomics) ------
__global__ __launch_bounds__(256) void fused_router_kernel(
    const float* __restrict__ x, const float* __restrict__ Wr,
    const float* __restrict__ br, unsigned short* __restrict__ xb,
    float* __restrict__ probs_out, int* __restrict__ routes) {
  __shared__ float WrL[NEXP][DIN];   // transposed router weights, 32 KB
  const int tid = threadIdx.x;
#pragma unroll
  for (int rr = 0; rr < 4; ++rr) {
    int row = tid * 4 + rr;
    float4 w0 = *(const float4*)(Wr + (size_t)row * NEXP);
    float4 w1 = *(const float4*)(Wr + (size_t)row * NEXP + 4);
    WrL[0][row] = w0.x; WrL[1][row] = w0.y; WrL[2][row] = w0.z; WrL[3][row] = w0.w;
    WrL[4][row] = w1.x; WrL[5][row] = w1.y; WrL[6][row] = w1.z; WrL[7][row] = w1.w;
  }
  __syncthreads();

  const int lane = tid & 63;
  const int n = blockIdx.x * 4 + (tid >> 6);
  const float4* xr = (const float4*)(x + (size_t)n * DIN);
  ushort4* xo = (ushort4*)(xb + (size_t)n * DIN);
  float acc[NEXP];
#pragma unroll
  for (int e = 0; e < NEXP; ++e) acc[e] = 0.f;
#pragma unroll
  for (int j = 0; j < 4; ++j) {
    int idx = j * 64 + lane;            // coalesced: 64 consecutive float4
    float4 xv = xr[idx];
    ushort4 o = { f2bf(xv.x), f2bf(xv.y), f2bf(xv.z), f2bf(xv.w) };
    xo[idx] = o;
    int r0 = idx * 4;
#pragma unroll
    for (int e = 0; e < NEXP; ++e) {
      float4 wv = *(const float4*)&WrL[e][r0];
      acc[e] += xv.x * wv.x + xv.y * wv.y + xv.z * wv.z + xv.w * wv.w;
    }
  }
#pragma unroll
  for (int m = 1; m < 64; m <<= 1)
#pragma unroll
    for (int e = 0; e < NEXP; ++e) acc[e] += __shfl_xor(acc[e], m);

  if (lane == 0) {
    float lg[NEXP], p[NEXP];
    float mx = -1e30f;
#pragma unroll
    for (int e = 0; e < NEXP; ++e) { lg[e] = acc[e] + br[e]; mx = fmaxf(mx, lg[e]); }
    float s = 0.f;
#pragma unroll
    for (int e = 0; e < NEXP; ++e) { p[e] = expf(lg[e] - mx); s += p[e]; }
    float inv = 1.f / s;
    int best = 0; float bp = -1.f;
#pragma unroll
    for (int e = 0; e < NEXP; ++e) {
      p[e] *= inv;
      probs_out[(size_t)n * NEXP + e] = p[e];
      if (p[e] > bp) { bp = p[e]; best = e; }   // strict > : first-index tie-break
    }
    routes[n] = best;
  }
}

// ---------------- histogram + scan (single block, no atomics) ----------------
__global__ __launch_bounds__(256) void hist_scan_kernel(
    const int* __restrict__ routes, int* __restrict__ pad_off,
    int2* __restrict__ tile_table, float* __restrict__ counts_out) {
  __shared__ int wsum[4][NEXP];
  const int tid = threadIdx.x;
  const int lane = tid & 63, w = tid >> 6;
  int cnt[NEXP];
#pragma unroll
  for (int e = 0; e < NEXP; ++e) cnt[e] = 0;
#pragma unroll
  for (int j = 0; j < 8; ++j) {
    int4 r4 = ((const int4*)routes)[tid + 256 * j];
    int rr[4] = {r4.x, r4.y, r4.z, r4.w};
#pragma unroll
    for (int i = 0; i < 4; ++i)
#pragma unroll
      for (int e = 0; e < NEXP; ++e) cnt[e] += (rr[i] == e);  // no runtime idx -> regs
  }
#pragma unroll
  for (int m = 1; m < 64; m <<= 1)
#pragma unroll
    for (int e = 0; e < NEXP; ++e) cnt[e] += __shfl_xor(cnt[e], m);
  if (lane == 0)
#pragma unroll
    for (int e = 0; e < NEXP; ++e) wsum[w][e] = cnt[e];
  __syncthreads();
  if (tid == 0) {
    int off = 0, t = 0;
    for (int e = 0; e < NEXP; ++e) {
      int c = wsum[0][e] + wsum[1][e] + wsum[2][e] + wsum[3][e];
      pad_off[e] = off;
      counts_out[e] = (float)c;
      int tiles = (c + BM - 1) / BM;
      for (int i = 0; i < tiles; ++i) { tile_table[t] = make_int2(e, off + i * BM); ++t; }
      off += tiles * BM;
    }
    for (; t < MAXT; ++t) tile_table[t] = make_int2(-1, 0);
  }
}

// ---------------- build sorted token list (wave-aggregated atomics) ---------
__global__ void build_kernel(const int* __restrict__ routes,
                             const int* __restrict__ pad_off,
                             int* __restrict__ cursor,
                             int* __restrict__ sorted) {
  const int n = blockIdx.x * 256 + threadIdx.x;
  const int lane = threadIdx.x & 63;
  const int e = routes[n];
#pragma unroll
  for (int ex = 0; ex < NEXP; ++ex) {
    unsigned long long m = __ballot(e == ex);
    if (e == ex) {
      int leader = __ffsll(m) - 1;
      int rank = __popcll(m & ((1ull << lane) - 1ull));
      int b = 0;
      if (rank == 0) b = atomicAdd(&cursor[ex], (int)__popcll(m));
      b = __shfl(b, leader);
      sorted[pad_off[ex] + b + rank] = n;
    }
  }
}

// ---------------- grouped GEMM: 4-slot ring + REGISTER frag double-buffer ---
// 8 waves (2M x 4N). One raw s_barrier per K-step. Iter t:
//   wait_vm(<=1 tile in flight beyond t+1) -> tile t+1 LDS-complete (per wave)
//   wait_lgkm(GUARD)   -> frag-reads of tile t-1 drained (slot (t-1)&3 free)
//   s_barrier          -> both facts now hold across ALL waves
//   stage(t+3)         -> writes slot (t-1)&3 (safe by the guard)
//   ds_read frags(t+1) -> into the spare reg set (no dep for this iter's MFMA)
//   MFMA(t)            -> consumes regs loaded LAST iter; overlaps the reads
// DBB=false: B frags single-buffered (read tile t's B in-iter; saves VGPRs,
// GUARD=8 keeps only A(t+1) reads in flight). DBB=true: full double-buffer,
// GUARD=8+NF. Chunk XOR swizzle (c ^= (row&3)^((row>>2)&3), involution) on
// BOTH global source and ds_read address (rule #21).
// MODE 0: A = xb,   out = relu(acc+b1) -> bf16 hbuf[token][NDIM]
// MODE 1: A = hbuf, out = acc+b2       -> fp32 out[token][NDIM]
template <int KDIM, int MODE, int BN_, int NB, bool DBB>
__global__ __launch_bounds__(512, 2) void gemm_moe(
    const unsigned short* __restrict__ A, const unsigned short* __restrict__ WT,
    const float* __restrict__ bias, const int* __restrict__ sorted,
    const int2* __restrict__ tile_table, void* __restrict__ Cout, int NDIM) {
  constexpr int SLOT_A = BM * BK;            // 8192 shorts
  constexpr int SLOT_B = BN_ * BK;
  constexpr int SLOTT = SLOT_A + SLOT_B;
  constexpr int CPT = (BM + BN_) * 4 / 512;  // 16B chunks per thread per tile
  constexpr int WN = BN_ / 4;                // wave N extent
  constexpr int NF = WN / 16;                // N fragments per wave
  constexpr int GUARD = DBB ? (8 + NF) : 8;
  __shared__ short lds[4 * SLOTT];

  // T1 bijective XCD swizzle (nwg % 8 == 0)
  const int nwg = NB * MAXT;
  const int bid = blockIdx.x;
  const int swz = (bid & 7) * (nwg >> 3) + (bid >> 3);
  const int2 tt = tile_table[swz / NB];
  if (tt.x < 0) return;
  const int expert = tt.x, mbase = tt.y;
  const int n0 = (swz % NB) * BN_;
  const int tid = threadIdx.x, lane = tid & 63, w = tid >> 6;

  // ---- staging descriptors: CPT 16B-chunks per thread per K-tile
  const short* src[CPT];
  int dst[CPT];
#pragma unroll
  for (int i = 0; i < CPT; ++i) {
    const int ci = i * 512 + tid;           // global chunk id (A then B)
    if (i < (BM * 4) / 512) {               // A chunk (compile-time per i)
      const int row = ci >> 2, c = ci & 3;
      const int csw = (c ^ (row & 3) ^ ((row >> 2) & 3)) * 8;
      int tok = sorted[mbase + row];
      if (tok < 0) tok = 0;                 // pad: finite garbage, dropped at store
      src[i] = (const short*)A + (size_t)tok * KDIM + csw;
      dst[i] = ci * 8;                      // linear LDS dest (lane-contiguous)
    } else {                                // B chunk
      const int bc = ci - BM * 4;
      const int row = bc >> 2, c = bc & 3;
      const int csw = (c ^ (row & 3) ^ ((row >> 2) & 3)) * 8;
      src[i] = (const short*)WT + ((size_t)expert * NDIM + n0 + row) * KDIM + csw;
      dst[i] = SLOT_A + bc * 8;
    }
  }

  // ---- fragment read offsets (within a slot, shorts)
  const int wm = w >> 2, wn = w & 3;        // wave grid 2 x 4
  const int fr = lane & 15, klo = lane >> 4;
  int aoff[8], boff[NF];
#pragma unroll
  for (int m = 0; m < 8; ++m) {
    int r = wm * 128 + m * 16 + fr;
    aoff[m] = r * BK + ((klo ^ (r & 3) ^ ((r >> 2) & 3)) << 3);
  }
#pragma unroll
  for (int n = 0; n < NF; ++n) {
    int r = wn * WN + n * 16 + fr;
    boff[n] = SLOT_A + r * BK + ((klo ^ (r & 3) ^ ((r >> 2) & 3)) << 3);
  }

  f32x4 acc[8][NF];
#pragma unroll
  for (int m = 0; m < 8; ++m)
#pragma unroll
    for (int n = 0; n < NF; ++n) acc[m][n] = (f32x4){0.f, 0.f, 0.f, 0.f};

  auto stage = [&](int t) {
    const int sb = (t & 3) * SLOTT, k0 = t * BK;
#pragma unroll
    for (int i = 0; i < CPT; ++i) gload_lds16(src[i] + k0, &lds[sb + dst[i]]);
  };
  auto ldA = [&](int t, short8 (&fa)[8]) {
    const short* sl = &lds[(t & 3) * SLOTT];
#pragma unroll
    for (int m = 0; m < 8; ++m) fa[m] = *(const short8*)&sl[aoff[m]];
  };
  auto ldB = [&](int t, short8 (&fb)[NF]) {
    const short* sl = &lds[(t & 3) * SLOTT];
#pragma unroll
    for (int n = 0; n < NF; ++n) fb[n] = *(const short8*)&sl[boff[n]];
  };
  auto domfma = [&](short8 (&fa)[8], short8 (&fb)[NF]) {
    __builtin_amdgcn_s_setprio(1);
#pragma unroll
    for (int m = 0; m < 8; ++m)
#pragma unroll
      for (int n = 0; n < NF; ++n)
        acc[m][n] = __builtin_amdgcn_mfma_f32_16x16x32_bf16(fa[m], fb[n], acc[m][n], 0, 0, 0);
    __builtin_amdgcn_s_setprio(0);
  };

  constexpr int NT = KDIM / BK;   // even (32 or 64)
  stage(0); stage(1); stage(2);
  wait_vm<2 * CPT>();
  __builtin_amdgcn_s_barrier();
  __builtin_amdgcn_sched_barrier(0);

  short8 faA[8], faB[8], fbA[NF], fbB[NF];
  ldA(0, faA);
  if constexpr (DBB) ldB(0, fbA);

  for (int t = 0; t < NT; t += 2) {
    // ---- even sub-iter: compute tile t (A-set), prefetch t+1 into B-set
    if (t + 2 <= NT - 1) wait_vm<CPT>(); else wait_vm<0>();
    wait_lgkm<GUARD>();
    __builtin_amdgcn_s_barrier();
    __builtin_amdgcn_sched_barrier(0);
    if (t + 3 < NT) stage(t + 3);
    if constexpr (!DBB) ldB(t, fbA);
    ldA(t + 1, faB);
    if constexpr (DBB) ldB(t + 1, fbB);
    domfma(faA, fbA);
    // ---- odd sub-iter: compute tile t+1 (B-set), prefetch t+2 into A-set
    if (t + 3 <= NT - 1) wait_vm<CPT>(); else wait_vm<0>();
    wait_lgkm<GUARD>();
    __builtin_amdgcn_s_barrier();
    __builtin_amdgcn_sched_barrier(0);
    if (t + 4 < NT) stage(t + 4);
    if constexpr (!DBB) ldB(t + 1, fbB);
    if (t + 2 < NT) {
      ldA(t + 2, faA);
      if constexpr (DBB) ldB(t + 2, fbA);
    }
    domfma(faB, fbB);
  }

  // ---- epilogue: scatter rows to token-indexed buffer
  const int fq = lane >> 4;
#pragma unroll
  for (int m = 0; m < 8; ++m) {
    int tok[4];
#pragma unroll
    for (int r = 0; r < 4; ++r)
      tok[r] = sorted[mbase + wm * 128 + m * 16 + fq * 4 + r];
#pragma unroll
    for (int n = 0; n < NF; ++n) {
      const int col = n0 + wn * WN + n * 16 + fr;
      const float bv = bias[(size_t)expert * NDIM + col];
#pragma unroll
      for (int r = 0; r < 4; ++r) {
        if (tok[r] < 0) continue;           // pad row
        float v = acc[m][n][r] + bv;
        if (MODE == 0) {
          ((unsigned short*)Cout)[(size_t)tok[r] * NDIM + col] = f2bf(fmaxf(v, 0.f));
        } else {
          ((float*)Cout)[(size_t)tok[r] * NDIM + col] = v;
        }
      }
    }
  }
}

extern "C" void kernel_launch(void* const* d_in, const int* in_sizes, int n_in,
                              void* d_out, int out_size, void* d_ws, size_t ws_size,
                              hipStream_t stream) {
  const float* x  = (const float*)d_in[0];
  const float* Wr = (const float*)d_in[1];
  const float* br = (const float*)d_in[2];
  const float* W1 = (const float*)d_in[3];
  const float* b1 = (const float*)d_in[4];
  const float* W2 = (const float*)d_in[5];
  const float* b2 = (const float*)d_in[6];

  float* out_y      = (float*)d_out;                      // [N,O]
  float* out_probs  = out_y + (size_t)NTOK * OUTD;        // [N,E]
  float* out_counts = out_probs + (size_t)NTOK * NEXP;    // [E]

  char* ws = (char*)d_ws;
  unsigned short* xb   = (unsigned short*)(ws);                                  // 16 MB
  unsigned short* w1t  = (unsigned short*)(ws + 16777216ULL);                    // 32 MB
  unsigned short* w2t  = (unsigned short*)(ws + 50331648ULL);                    // 32 MB
  unsigned short* hbuf = (unsigned short*)(ws + 83886080ULL);                    // 32 MB (token-indexed)
  char* p = ws + 117440512ULL;
  int* routes   = (int*)p; p += 32768;
  int* sorted   = (int*)p; p += (NTOK + NEXP * BM) * 4;   // 40960 B
  int* cursor   = (int*)p; p += 256;
  int* pad_off  = (int*)p; p += 256;
  int2* tt      = (int2*)p;

  hipMemsetAsync(sorted, 0xFF, (NTOK + NEXP * BM) * sizeof(int), stream);
  hipMemsetAsync(cursor, 0, 256, stream);

  transpose_convert_kernel<<<dim3(HID / 64, DIN / 64, NEXP), 256, 0, stream>>>(W1, w1t, DIN, HID);
  transpose_convert_kernel<<<dim3(OUTD / 64, HID / 64, NEXP), 256, 0, stream>>>(W2, w2t, HID, OUTD);
  fused_router_kernel<<<NTOK / 4, 256, 0, stream>>>(x, Wr, br, xb, out_probs, routes);
  hist_scan_kernel<<<1, 256, 0, stream>>>(routes, pad_off, tt, out_counts);
  build_kernel<<<NTOK / 256, 256, 0, stream>>>(routes, pad_off, cursor, sorted);
  gemm_moe<DIN, 0, 256, HID / 256, false><<<(HID / 256) * MAXT, 512, 0, stream>>>(
      xb, w1t, b1, sorted, tt, hbuf, HID);
  gemm_moe<HID, 1, 128, OUTD / 128, true><<<(OUTD / 128) * MAXT, 512, 0, stream>>>(
      hbuf, w2t, b2, sorted, tt, out_y, OUTD);
}

// Round 9
// 231.414 us; speedup vs baseline: 1.2411x; 1.0556x over previous
//
#include <hip/hip_runtime.h>
#include <hip/hip_bf16.h>

#define NTOK 8192
#define DIN  1024
#define HID  2048
#define OUTD 1024
#define NEXP 8
#define BM 256
#define MAXT (NTOK / BM + NEXP)   // 40 M-tiles max

typedef short short8 __attribute__((ext_vector_type(8)));
typedef float f32x4 __attribute__((ext_vector_type(4)));

static __device__ __forceinline__ unsigned short f2bf(float f) {
  union { __hip_bfloat16 b; unsigned short u; } cv;
  cv.b = __float2bfloat16(f);
  return cv.u;
}

static __device__ __forceinline__ void gload_lds16(const void* g, void* l) {
  __builtin_amdgcn_global_load_lds(
      (const __attribute__((address_space(1))) void*)g,
      (__attribute__((address_space(3))) void*)l, 16, 0, 0);
}

// ---------------- prep: W [E][R][C] fp32 -> WT [E][C][R] bf16 ----------------
__global__ __launch_bounds__(256) void transpose_convert_kernel(
    const float* __restrict__ W, unsigned short* __restrict__ WT, int R, int C) {
  __shared__ float tile[64][65];
  const int e = blockIdx.z;
  const int c0 = blockIdx.x * 64, r0 = blockIdx.y * 64;
  const int lr = threadIdx.x >> 4;    // 0..15
  const int fc = threadIdx.x & 15;    // float4 column
  const float* Wp = W + ((size_t)e * R + r0) * C + c0;
#pragma unroll
  for (int i = 0; i < 4; ++i) {
    int r = lr + i * 16;
    float4 v = *(const float4*)(Wp + (size_t)r * C + fc * 4);
    tile[r][fc * 4 + 0] = v.x; tile[r][fc * 4 + 1] = v.y;
    tile[r][fc * 4 + 2] = v.z; tile[r][fc * 4 + 3] = v.w;
  }
  __syncthreads();
  unsigned short* Op = WT + ((size_t)e * C + c0) * R + r0;
#pragma unroll
  for (int i = 0; i < 4; ++i) {
    int cc = lr + i * 16;             // output row = source col
    int rb = fc * 4;                  // 4 source rows
    ushort4 o = { f2bf(tile[rb + 0][cc]), f2bf(tile[rb + 1][cc]),
                  f2bf(tile[rb + 2][cc]), f2bf(tile[rb + 3][cc]) };
    *(ushort4*)(Op + (size_t)cc * R + rb) = o;
  }
}

// ---------------- fused: x fp32 -> bf16  +  router (fp32, NO atomics) ------
__global__ __launch_bounds__(256) void fused_router_kernel(
    const float* __restrict__ x, const float* __restrict__ Wr,
    const float* __restrict__ br, unsigned short* __restrict__ xb,
    float* __restrict__ probs_out, int* __restrict__ routes) {
  __shared__ float WrL[NEXP][DIN];   // transposed router weights, 32 KB
  const int tid = threadIdx.x;
#pragma unroll
  for (int rr = 0; rr < 4; ++rr) {
    int row = tid * 4 + rr;
    float4 w0 = *(const float4*)(Wr + (size_t)row * NEXP);
    float4 w1 = *(const float4*)(Wr + (size_t)row * NEXP + 4);
    WrL[0][row] = w0.x; WrL[1][row] = w0.y; WrL[2][row] = w0.z; WrL[3][row] = w0.w;
    WrL[4][row] = w1.x; WrL[5][row] = w1.y; WrL[6][row] = w1.z; WrL[7][row] = w1.w;
  }
  __syncthreads();

  const int lane = tid & 63;
  const int n = blockIdx.x * 4 + (tid >> 6);
  const float4* xr = (const float4*)(x + (size_t)n * DIN);
  ushort4* xo = (ushort4*)(xb + (size_t)n * DIN);
  float acc[NEXP];
#pragma unroll
  for (int e = 0; e < NEXP; ++e) acc[e] = 0.f;
#pragma unroll
  for (int j = 0; j < 4; ++j) {
    int idx = j * 64 + lane;            // coalesced: 64 consecutive float4
    float4 xv = xr[idx];
    ushort4 o = { f2bf(xv.x), f2bf(xv.y), f2bf(xv.z), f2bf(xv.w) };
    xo[idx] = o;
    int r0 = idx * 4;
#pragma unroll
    for (int e = 0; e < NEXP; ++e) {
      float4 wv = *(const float4*)&WrL[e][r0];
      acc[e] += xv.x * wv.x + xv.y * wv.y + xv.z * wv.z + xv.w * wv.w;
    }
  }
#pragma unroll
  for (int m = 1; m < 64; m <<= 1)
#pragma unroll
    for (int e = 0; e < NEXP; ++e) acc[e] += __shfl_xor(acc[e], m);

  if (lane == 0) {
    float lg[NEXP], p[NEXP];
    float mx = -1e30f;
#pragma unroll
    for (int e = 0; e < NEXP; ++e) { lg[e] = acc[e] + br[e]; mx = fmaxf(mx, lg[e]); }
    float s = 0.f;
#pragma unroll
    for (int e = 0; e < NEXP; ++e) { p[e] = expf(lg[e] - mx); s += p[e]; }
    float inv = 1.f / s;
    int best = 0; float bp = -1.f;
#pragma unroll
    for (int e = 0; e < NEXP; ++e) {
      p[e] *= inv;
      probs_out[(size_t)n * NEXP + e] = p[e];
      if (p[e] > bp) { bp = p[e]; best = e; }   // strict > : first-index tie-break
    }
    routes[n] = best;
  }
}

// ---------------- histogram + scan (single block, no atomics) ----------------
__global__ __launch_bounds__(256) void hist_scan_kernel(
    const int* __restrict__ routes, int* __restrict__ pad_off,
    int2* __restrict__ tile_table, float* __restrict__ counts_out) {
  __shared__ int wsum[4][NEXP];
  const int tid = threadIdx.x;
  const int lane = tid & 63, w = tid >> 6;
  int cnt[NEXP];
#pragma unroll
  for (int e = 0; e < NEXP; ++e) cnt[e] = 0;
#pragma unroll
  for (int j = 0; j < 8; ++j) {
    int4 r4 = ((const int4*)routes)[tid + 256 * j];
    int rr[4] = {r4.x, r4.y, r4.z, r4.w};
#pragma unroll
    for (int i = 0; i < 4; ++i)
#pragma unroll
      for (int e = 0; e < NEXP; ++e) cnt[e] += (rr[i] == e);  // no runtime idx -> regs
  }
#pragma unroll
  for (int m = 1; m < 64; m <<= 1)
#pragma unroll
    for (int e = 0; e < NEXP; ++e) cnt[e] += __shfl_xor(cnt[e], m);
  if (lane == 0)
#pragma unroll
    for (int e = 0; e < NEXP; ++e) wsum[w][e] = cnt[e];
  __syncthreads();
  if (tid == 0) {
    int off = 0, t = 0;
    for (int e = 0; e < NEXP; ++e) {
      int c = wsum[0][e] + wsum[1][e] + wsum[2][e] + wsum[3][e];
      pad_off[e] = off;
      counts_out[e] = (float)c;
      int tiles = (c + BM - 1) / BM;
      for (int i = 0; i < tiles; ++i) { tile_table[t] = make_int2(e, off + i * BM); ++t; }
      off += tiles * BM;
    }
    for (; t < MAXT; ++t) tile_table[t] = make_int2(-1, 0);
  }
}

// ---------------- build sorted token list (wave-aggregated atomics) ---------
__global__ void build_kernel(const int* __restrict__ routes,
                             const int* __restrict__ pad_off,
                             int* __restrict__ cursor,
                             int* __restrict__ sorted) {
  const int n = blockIdx.x * 256 + threadIdx.x;
  const int lane = threadIdx.x & 63;
  const int e = routes[n];
#pragma unroll
  for (int ex = 0; ex < NEXP; ++ex) {
    unsigned long long m = __ballot(e == ex);
    if (e == ex) {
      int leader = __ffsll(m) - 1;
      int rank = __popcll(m & ((1ull << lane) - 1ull));
      int b = 0;
      if (rank == 0) b = atomicAdd(&cursor[ex], (int)__popcll(m));
      b = __shfl(b, leader);
      sorted[pad_off[ex] + b + rank] = n;
    }
  }
}

// ============ grouped GEMM: m201-style 8-phase 256x256, BK=64 ==============
// 8 waves, wave grid 4M x 2N PER QUADRANT: each phase computes one 128x128
// C-quadrant (Mh,Nh), reading ONLY A-half Mh and B-half Nh. LDS = 2 dbuf x
// [A0|A1|B0|B1] x 16KB = 128 KB; K-tile t lives in dbuf t&1. Per K-tile quad
// order (M0N0)(M1N0)(M1N1)(M0N1); stage slots (derived, half-disjoint from
// all concurrent reads): q1->B1(t+1), q2->A0(t+1), q3->B0(t+2), q4->A1(t+2).
// vmcnt(4) once per K-tile (at q4) => newest half needed next quad (A0(t+1),
// issued 2 half-tiles = 4 loads back) complete; raw s_barrier (no drain) +
// lgkmcnt(0)+sched_barrier (rule #18). T2 st_16x32 swizzle byte^=((b>>9)&1)<<5
// applied on pre-swizzled gload source AND ds_read address (rule #21).
// MODE 0: A = xb gathered, out = relu(acc+b1) -> bf16 hbuf[token][NDIM]
// MODE 1: A = hbuf gathered, out = acc+b2     -> fp32 out[token][NDIM]
#define BAR0() do { __builtin_amdgcn_s_barrier(); \
    __builtin_amdgcn_sched_barrier(0); \
    asm volatile("s_waitcnt lgkmcnt(0)" ::: "memory"); \
    __builtin_amdgcn_sched_barrier(0); } while (0)
#define BARC() do { __builtin_amdgcn_s_barrier(); \
    __builtin_amdgcn_sched_barrier(0); } while (0)
#define VM4()  asm volatile("s_waitcnt vmcnt(4)" ::: "memory")

#define LDA(MH, D) \
  _Pragma("unroll") for (int i_ = 0; i_ < 2; ++i_) \
  _Pragma("unroll") for (int k_ = 0; k_ < 2; ++k_) \
    fa[MH][i_][k_] = *(const short8*)&lds[(D) + (MH) * 8192 + aoff[i_][k_]];
#define LDB(NH, D) \
  _Pragma("unroll") for (int j_ = 0; j_ < 4; ++j_) \
  _Pragma("unroll") for (int k_ = 0; k_ < 2; ++k_) \
    fb[j_][k_] = *(const short8*)&lds[(D) + 16384 + (NH) * 8192 + boff[j_][k_]];
#define MFMA_QUAD(MH, NH) do { __builtin_amdgcn_s_setprio(1); \
  _Pragma("unroll") for (int i_ = 0; i_ < 2; ++i_) \
  _Pragma("unroll") for (int j_ = 0; j_ < 4; ++j_) \
  _Pragma("unroll") for (int k_ = 0; k_ < 2; ++k_) \
    acc[(MH) * 2 + i_][(NH) * 4 + j_] = __builtin_amdgcn_mfma_f32_16x16x32_bf16( \
        fa[MH][i_][k_], fb[j_][k_], acc[(MH) * 2 + i_][(NH) * 4 + j_], 0, 0, 0); \
  __builtin_amdgcn_s_setprio(0); } while (0)

template <int KDIM, int MODE, int NB>
__global__ __launch_bounds__(512, 2) void gemm_moe(
    const unsigned short* __restrict__ A, const unsigned short* __restrict__ WT,
    const float* __restrict__ bias, const int* __restrict__ sorted,
    const int2* __restrict__ tile_table, void* __restrict__ Cout, int NDIM) {
  __shared__ short lds[65536];   // 128 KB

  // T1 bijective XCD swizzle (nwg % 8 == 0)
  const int nwg = NB * MAXT;
  const int bid = blockIdx.x;
  const int swz = (bid & 7) * (nwg >> 3) + (bid >> 3);
  const int2 tt = tile_table[swz / NB];
  if (tt.x < 0) return;
  const int expert = tt.x, mbase = tt.y;
  const int n0 = (swz % NB) * 256;
  const int tid = threadIdx.x, lane = tid & 63, w = tid >> 6;
  const int qm = w >> 1, qn = w & 1;       // wave grid 4M x 2N within a quadrant
  const int fr = lane & 15, klo = lane >> 4;

  // ---- staging descriptors: 2 x 16B chunks per thread per half-tile ----
  const short* srcA[2][2];   // [half][load]
  const short* srcB[2][2];
  int dstoff[2];
#pragma unroll
  for (int l = 0; l < 2; ++l) {
    const int ch = l * 512 + tid;                       // phys chunk in half
    const int lch = ch ^ (((ch >> 5) & 1) << 1);        // logical (pre-swizzle)
    const int row = lch >> 3, cs = (lch & 7) * 8;
    dstoff[l] = ch * 8;                                 // linear LDS dest
#pragma unroll
    for (int h = 0; h < 2; ++h) {
      int tok = sorted[mbase + h * 128 + row];
      if (tok < 0) tok = 0;                             // pad: dropped at store
      srcA[h][l] = (const short*)A + (size_t)tok * KDIM + cs;
      srcB[h][l] = (const short*)WT + ((size_t)expert * NDIM + n0 + h * 128 + row) * KDIM + cs;
    }
  }
  auto stA = [&](int doff, int h, int kt) {
    const int base = doff + h * 8192, ko = kt * 64;
#pragma unroll
    for (int l = 0; l < 2; ++l) gload_lds16(srcA[h][l] + ko, &lds[base + dstoff[l]]);
  };
  auto stB = [&](int doff, int h, int kt) {
    const int base = doff + 16384 + h * 8192, ko = kt * 64;
#pragma unroll
    for (int l = 0; l < 2; ++l) gload_lds16(srcB[h][l] + ko, &lds[base + dstoff[l]]);
  };

  // ---- fragment ds_read offsets (shorts, within half-block, swizzled) ----
  int aoff[2][2], boff[4][2];
#pragma unroll
  for (int i = 0; i < 2; ++i)
#pragma unroll
    for (int k = 0; k < 2; ++k) {
      int b = (qm * 32 + i * 16 + fr) * 128 + k * 64 + klo * 16;
      b ^= ((b >> 9) & 1) << 5;
      aoff[i][k] = b >> 1;
    }
#pragma unroll
  for (int j = 0; j < 4; ++j)
#pragma unroll
    for (int k = 0; k < 2; ++k) {
      int b = (qn * 64 + j * 16 + fr) * 128 + k * 64 + klo * 16;
      b ^= ((b >> 9) & 1) << 5;
      boff[j][k] = b >> 1;
    }

  f32x4 acc[4][8];
#pragma unroll
  for (int mi = 0; mi < 4; ++mi)
#pragma unroll
    for (int nj = 0; nj < 8; ++nj) acc[mi][nj] = (f32x4){0.f, 0.f, 0.f, 0.f};
  short8 fa[2][2][2], fb[4][2];

  constexpr int NKT = KDIM / 64;
  // prologue: tile0 all halves + B0(1), A1(1)  (order matters for vmcnt(4))
  stB(0, 0, 0); stA(0, 1, 0); stB(0, 1, 0); stA(0, 0, 0);
  stB(32768, 0, 1); stA(32768, 1, 1);
  VM4();
  BARC();

  for (int t = 0; t < NKT; ++t) {
    const int d = (t & 1) * 32768;
    const int dn = 32768 - d;
    // q1 (M0,N0): read A0,B0; stage B1(t+1)
    LDA(0, d); LDB(0, d);
    if (t + 1 < NKT) stB(dn, 1, t + 1);
    BAR0();
    MFMA_QUAD(0, 0);
    BARC();
    // q2 (M1,N0): read A1; stage A0(t+1)
    LDA(1, d);
    if (t + 1 < NKT) stA(dn, 0, t + 1);
    BAR0();
    MFMA_QUAD(1, 0);
    BARC();
    // q3 (M1,N1): read B1; stage B0(t+2)
    LDB(1, d);
    if (t + 2 < NKT) stB(d, 0, t + 2);
    BAR0();
    MFMA_QUAD(1, 1);
    BARC();
    // q4 (M0,N1): stage A1(t+2); vmcnt(4) once per K-tile
    if (t + 2 < NKT) stA(d, 1, t + 2);
    BAR0();
    MFMA_QUAD(0, 1);
    VM4();
    BARC();
  }

  // ---- epilogue: scatter rows to token-indexed buffer ----
  const int fq = lane >> 4;
#pragma unroll
  for (int mi = 0; mi < 4; ++mi) {
    const int rbase = mbase + (mi >> 1) * 128 + qm * 32 + (mi & 1) * 16 + fq * 4;
    int tok[4];
#pragma unroll
    for (int r = 0; r < 4; ++r) tok[r] = sorted[rbase + r];
#pragma unroll
    for (int nj = 0; nj < 8; ++nj) {
      const int col = n0 + (nj >> 2) * 128 + qn * 64 + (nj & 3) * 16 + fr;
      const float bv = bias[(size_t)expert * NDIM + col];
#pragma unroll
      for (int r = 0; r < 4; ++r) {
        if (tok[r] < 0) continue;           // pad row
        float v = acc[mi][nj][r] + bv;
        if (MODE == 0) {
          ((unsigned short*)Cout)[(size_t)tok[r] * NDIM + col] = f2bf(fmaxf(v, 0.f));
        } else {
          ((float*)Cout)[(size_t)tok[r] * NDIM + col] = v;
        }
      }
    }
  }
}

extern "C" void kernel_launch(void* const* d_in, const int* in_sizes, int n_in,
                              void* d_out, int out_size, void* d_ws, size_t ws_size,
                              hipStream_t stream) {
  const float* x  = (const float*)d_in[0];
  const float* Wr = (const float*)d_in[1];
  const float* br = (const float*)d_in[2];
  const float* W1 = (const float*)d_in[3];
  const float* b1 = (const float*)d_in[4];
  const float* W2 = (const float*)d_in[5];
  const float* b2 = (const float*)d_in[6];

  float* out_y      = (float*)d_out;                      // [N,O]
  float* out_probs  = out_y + (size_t)NTOK * OUTD;        // [N,E]
  float* out_counts = out_probs + (size_t)NTOK * NEXP;    // [E]

  char* ws = (char*)d_ws;
  unsigned short* xb   = (unsigned short*)(ws);                                  // 16 MB
  unsigned short* w1t  = (unsigned short*)(ws + 16777216ULL);                    // 32 MB
  unsigned short* w2t  = (unsigned short*)(ws + 50331648ULL);                    // 32 MB
  unsigned short* hbuf = (unsigned short*)(ws + 83886080ULL);                    // 32 MB (token-indexed)
  char* p = ws + 117440512ULL;
  int* routes   = (int*)p; p += 32768;
  int* sorted   = (int*)p; p += (NTOK + NEXP * BM) * 4;   // 40960 B
  int* cursor   = (int*)p; p += 256;
  int* pad_off  = (int*)p; p += 256;
  int2* tt      = (int2*)p;

  hipMemsetAsync(sorted, 0xFF, (NTOK + NEXP * BM) * sizeof(int), stream);
  hipMemsetAsync(cursor, 0, 256, stream);

  transpose_convert_kernel<<<dim3(HID / 64, DIN / 64, NEXP), 256, 0, stream>>>(W1, w1t, DIN, HID);
  transpose_convert_kernel<<<dim3(OUTD / 64, HID / 64, NEXP), 256, 0, stream>>>(W2, w2t, HID, OUTD);
  fused_router_kernel<<<NTOK / 4, 256, 0, stream>>>(x, Wr, br, xb, out_probs, routes);
  hist_scan_kernel<<<1, 256, 0, stream>>>(routes, pad_off, tt, out_counts);
  build_kernel<<<NTOK / 256, 256, 0, stream>>>(routes, pad_off, cursor, sorted);
  gemm_moe<DIN, 0, HID / 256><<<(HID / 256) * MAXT, 512, 0, stream>>>(
      xb, w1t, b1, sorted, tt, hbuf, HID);
  gemm_moe<HID, 1, OUTD / 256><<<(OUTD / 256) * MAXT, 512, 0, stream>>>(
      hbuf, w2t, b2, sorted, tt, out_y, OUTD);
}

// Round 10
// 212.307 us; speedup vs baseline: 1.3528x; 1.0900x over previous
//
#include <hip/hip_runtime.h>
#include <hip/hip_bf16.h>

#define NTOK 8192
#define DIN  1024
#define HID  2048
#define OUTD 1024
#define NEXP 8
#define BM 256
#define MAXT (NTOK / BM + NEXP)   // 40 M-tiles max

typedef short short8 __attribute__((ext_vector_type(8)));
typedef float f32x4 __attribute__((ext_vector_type(4)));

static __device__ __forceinline__ unsigned short f2bf(float f) {
  union { __hip_bfloat16 b; unsigned short u; } cv;
  cv.b = __float2bfloat16(f);
  return cv.u;
}

static __device__ __forceinline__ void gload_lds16(const void* g, void* l) {
  __builtin_amdgcn_global_load_lds(
      (const __attribute__((address_space(1))) void*)g,
      (__attribute__((address_space(3))) void*)l, 16, 0, 0);
}

// ---------------- prep: W [E][R][C] fp32 -> WT [E][C][R] bf16 ----------------
__global__ __launch_bounds__(256) void transpose_convert_kernel(
    const float* __restrict__ W, unsigned short* __restrict__ WT, int R, int C) {
  __shared__ float tile[64][65];
  const int e = blockIdx.z;
  const int c0 = blockIdx.x * 64, r0 = blockIdx.y * 64;
  const int lr = threadIdx.x >> 4;    // 0..15
  const int fc = threadIdx.x & 15;    // float4 column
  const float* Wp = W + ((size_t)e * R + r0) * C + c0;
#pragma unroll
  for (int i = 0; i < 4; ++i) {
    int r = lr + i * 16;
    float4 v = *(const float4*)(Wp + (size_t)r * C + fc * 4);
    tile[r][fc * 4 + 0] = v.x; tile[r][fc * 4 + 1] = v.y;
    tile[r][fc * 4 + 2] = v.z; tile[r][fc * 4 + 3] = v.w;
  }
  __syncthreads();
  unsigned short* Op = WT + ((size_t)e * C + c0) * R + r0;
#pragma unroll
  for (int i = 0; i < 4; ++i) {
    int cc = lr + i * 16;             // output row = source col
    int rb = fc * 4;                  // 4 source rows
    ushort4 o = { f2bf(tile[rb + 0][cc]), f2bf(tile[rb + 1][cc]),
                  f2bf(tile[rb + 2][cc]), f2bf(tile[rb + 3][cc]) };
    *(ushort4*)(Op + (size_t)cc * R + rb) = o;
  }
}

// ---------------- fused: x fp32 -> bf16  +  router (fp32, NO atomics) ------
__global__ __launch_bounds__(256) void fused_router_kernel(
    const float* __restrict__ x, const float* __restrict__ Wr,
    const float* __restrict__ br, unsigned short* __restrict__ xb,
    float* __restrict__ probs_out, int* __restrict__ routes) {
  __shared__ float WrL[NEXP][DIN];   // transposed router weights, 32 KB
  const int tid = threadIdx.x;
#pragma unroll
  for (int rr = 0; rr < 4; ++rr) {
    int row = tid * 4 + rr;
    float4 w0 = *(const float4*)(Wr + (size_t)row * NEXP);
    float4 w1 = *(const float4*)(Wr + (size_t)row * NEXP + 4);
    WrL[0][row] = w0.x; WrL[1][row] = w0.y; WrL[2][row] = w0.z; WrL[3][row] = w0.w;
    WrL[4][row] = w1.x; WrL[5][row] = w1.y; WrL[6][row] = w1.z; WrL[7][row] = w1.w;
  }
  __syncthreads();

  const int lane = tid & 63;
  const int n = blockIdx.x * 4 + (tid >> 6);
  const float4* xr = (const float4*)(x + (size_t)n * DIN);
  ushort4* xo = (ushort4*)(xb + (size_t)n * DIN);
  float acc[NEXP];
#pragma unroll
  for (int e = 0; e < NEXP; ++e) acc[e] = 0.f;
#pragma unroll
  for (int j = 0; j < 4; ++j) {
    int idx = j * 64 + lane;            // coalesced: 64 consecutive float4
    float4 xv = xr[idx];
    ushort4 o = { f2bf(xv.x), f2bf(xv.y), f2bf(xv.z), f2bf(xv.w) };
    xo[idx] = o;
    int r0 = idx * 4;
#pragma unroll
    for (int e = 0; e < NEXP; ++e) {
      float4 wv = *(const float4*)&WrL[e][r0];
      acc[e] += xv.x * wv.x + xv.y * wv.y + xv.z * wv.z + xv.w * wv.w;
    }
  }
#pragma unroll
  for (int m = 1; m < 64; m <<= 1)
#pragma unroll
    for (int e = 0; e < NEXP; ++e) acc[e] += __shfl_xor(acc[e], m);

  if (lane == 0) {
    float lg[NEXP], p[NEXP];
    float mx = -1e30f;
#pragma unroll
    for (int e = 0; e < NEXP; ++e) { lg[e] = acc[e] + br[e]; mx = fmaxf(mx, lg[e]); }
    float s = 0.f;
#pragma unroll
    for (int e = 0; e < NEXP; ++e) { p[e] = expf(lg[e] - mx); s += p[e]; }
    float inv = 1.f / s;
    int best = 0; float bp = -1.f;
#pragma unroll
    for (int e = 0; e < NEXP; ++e) {
      p[e] *= inv;
      probs_out[(size_t)n * NEXP + e] = p[e];
      if (p[e] > bp) { bp = p[e]; best = e; }   // strict > : first-index tie-break
    }
    routes[n] = best;
  }
}

// ---------------- histogram + scan (single block, no atomics) ----------------
__global__ __launch_bounds__(256) void hist_scan_kernel(
    const int* __restrict__ routes, int* __restrict__ pad_off,
    int2* __restrict__ tile_table, float* __restrict__ counts_out) {
  __shared__ int wsum[4][NEXP];
  const int tid = threadIdx.x;
  const int lane = tid & 63, w = tid >> 6;
  int cnt[NEXP];
#pragma unroll
  for (int e = 0; e < NEXP; ++e) cnt[e] = 0;
#pragma unroll
  for (int j = 0; j < 8; ++j) {
    int4 r4 = ((const int4*)routes)[tid + 256 * j];
    int rr[4] = {r4.x, r4.y, r4.z, r4.w};
#pragma unroll
    for (int i = 0; i < 4; ++i)
#pragma unroll
      for (int e = 0; e < NEXP; ++e) cnt[e] += (rr[i] == e);  // no runtime idx -> regs
  }
#pragma unroll
  for (int m = 1; m < 64; m <<= 1)
#pragma unroll
    for (int e = 0; e < NEXP; ++e) cnt[e] += __shfl_xor(cnt[e], m);
  if (lane == 0)
#pragma unroll
    for (int e = 0; e < NEXP; ++e) wsum[w][e] = cnt[e];
  __syncthreads();
  if (tid == 0) {
    int off = 0, t = 0;
    for (int e = 0; e < NEXP; ++e) {
      int c = wsum[0][e] + wsum[1][e] + wsum[2][e] + wsum[3][e];
      pad_off[e] = off;
      counts_out[e] = (float)c;
      int tiles = (c + BM - 1) / BM;
      for (int i = 0; i < tiles; ++i) { tile_table[t] = make_int2(e, off + i * BM); ++t; }
      off += tiles * BM;
    }
    for (; t < MAXT; ++t) tile_table[t] = make_int2(-1, 0);
  }
}

// ---------------- build sorted token list (wave-aggregated atomics) ---------
__global__ void build_kernel(const int* __restrict__ routes,
                             const int* __restrict__ pad_off,
                             int* __restrict__ cursor,
                             int* __restrict__ sorted) {
  const int n = blockIdx.x * 256 + threadIdx.x;
  const int lane = threadIdx.x & 63;
  const int e = routes[n];
#pragma unroll
  for (int ex = 0; ex < NEXP; ++ex) {
    unsigned long long m = __ballot(e == ex);
    if (e == ex) {
      int leader = __ffsll(m) - 1;
      int rank = __popcll(m & ((1ull << lane) - 1ull));
      int b = 0;
      if (rank == 0) b = atomicAdd(&cursor[ex], (int)__popcll(m));
      b = __shfl(b, leader);
      sorted[pad_off[ex] + b + rank] = n;
    }
  }
}

// ============ grouped GEMM: m201 8-phase 256x256, BK=64, ONE barrier/phase ==
// 8 waves, wave grid 4M x 2N PER QUADRANT: each phase computes one 128x128
// C-quadrant (Mh,Nh). LDS = 2 dbuf x [A0|A1|B0|B1] x 16KB = 128 KB; tile t in
// dbuf t&1. Phase p (one raw s_barrier each): [ds_read frags(p); stage;
// barrier; lgkmcnt(0); MFMA(p)] -- the ds_reads issue in the same barrier
// interval as MFMA(p-1), hiding LDS latency under the matrix pipe (WAR on the
// frag regs orders them; HW hazard recognizer handles MFMA src protection).
// Stage plan per K-tile t (half-disjoint from all concurrent reads, ledger
// re-verified for 1-barrier): q1->B1(t+1)@dn, q2->A0(t+1)@dn, q3->B0(t+2)@d,
// q4->A1(t+2)@d. vmcnt(4) at q4 completes through A0(t+1) (12-deep FIFO).
// T2 st_16x32 swizzle byte^=((b>>9)&1)<<5 on pre-swizzled gload source AND
// ds_read address (rule #21). Raw barrier + lgkmcnt(0) + sched_barrier(0)
// fences (rule #18).
// MODE 0: A = xb gathered, out = relu(acc+b1) -> bf16 hbuf[token][NDIM]
// MODE 1: A = hbuf gathered, out = acc+b2     -> fp32 out[token][NDIM]
#define PHASE_SYNC() do { \
    __builtin_amdgcn_sched_barrier(0); \
    __builtin_amdgcn_s_barrier(); \
    __builtin_amdgcn_sched_barrier(0); \
    asm volatile("s_waitcnt lgkmcnt(0)" ::: "memory"); \
    __builtin_amdgcn_sched_barrier(0); } while (0)
#define VM4()  asm volatile("s_waitcnt vmcnt(4)" ::: "memory")

#define LDA(MH, D) \
  _Pragma("unroll") for (int i_ = 0; i_ < 2; ++i_) \
  _Pragma("unroll") for (int k_ = 0; k_ < 2; ++k_) \
    fa[MH][i_][k_] = *(const short8*)&lds[(D) + (MH) * 8192 + aoff[i_][k_]];
#define LDB(NH, D) \
  _Pragma("unroll") for (int j_ = 0; j_ < 4; ++j_) \
  _Pragma("unroll") for (int k_ = 0; k_ < 2; ++k_) \
    fb[j_][k_] = *(const short8*)&lds[(D) + 16384 + (NH) * 8192 + boff[j_][k_]];
#define MFMA_QUAD(MH, NH) do { __builtin_amdgcn_s_setprio(1); \
  _Pragma("unroll") for (int i_ = 0; i_ < 2; ++i_) \
  _Pragma("unroll") for (int j_ = 0; j_ < 4; ++j_) \
  _Pragma("unroll") for (int k_ = 0; k_ < 2; ++k_) \
    acc[(MH) * 2 + i_][(NH) * 4 + j_] = __builtin_amdgcn_mfma_f32_16x16x32_bf16( \
        fa[MH][i_][k_], fb[j_][k_], acc[(MH) * 2 + i_][(NH) * 4 + j_], 0, 0, 0); \
  __builtin_amdgcn_s_setprio(0); } while (0)

template <int KDIM, int MODE, int NB>
__global__ __launch_bounds__(512, 2) void gemm_moe(
    const unsigned short* __restrict__ A, const unsigned short* __restrict__ WT,
    const float* __restrict__ bias, const int* __restrict__ sorted,
    const int2* __restrict__ tile_table, void* __restrict__ Cout, int NDIM) {
  __shared__ short lds[65536];   // 128 KB

  // T1 bijective XCD swizzle (nwg % 8 == 0)
  const int nwg = NB * MAXT;
  const int bid = blockIdx.x;
  const int swz = (bid & 7) * (nwg >> 3) + (bid >> 3);
  const int2 tt = tile_table[swz / NB];
  if (tt.x < 0) return;
  const int expert = tt.x, mbase = tt.y;
  const int n0 = (swz % NB) * 256;
  const int tid = threadIdx.x, lane = tid & 63, w = tid >> 6;
  const int qm = w >> 1, qn = w & 1;       // wave grid 4M x 2N within a quadrant
  const int fr = lane & 15, klo = lane >> 4;

  // ---- staging descriptors: 2 x 16B chunks per thread per half-tile ----
  const short* srcA[2][2];   // [half][load]
  const short* srcB[2][2];
  int dstoff[2];
#pragma unroll
  for (int l = 0; l < 2; ++l) {
    const int ch = l * 512 + tid;                       // phys chunk in half
    const int lch = ch ^ (((ch >> 5) & 1) << 1);        // logical (pre-swizzle)
    const int row = lch >> 3, cs = (lch & 7) * 8;
    dstoff[l] = ch * 8;                                 // linear LDS dest
#pragma unroll
    for (int h = 0; h < 2; ++h) {
      int tok = sorted[mbase + h * 128 + row];
      if (tok < 0) tok = 0;                             // pad: dropped at store
      srcA[h][l] = (const short*)A + (size_t)tok * KDIM + cs;
      srcB[h][l] = (const short*)WT + ((size_t)expert * NDIM + n0 + h * 128 + row) * KDIM + cs;
    }
  }
  auto stA = [&](int doff, int h, int kt) {
    const int base = doff + h * 8192, ko = kt * 64;
#pragma unroll
    for (int l = 0; l < 2; ++l) gload_lds16(srcA[h][l] + ko, &lds[base + dstoff[l]]);
  };
  auto stB = [&](int doff, int h, int kt) {
    const int base = doff + 16384 + h * 8192, ko = kt * 64;
#pragma unroll
    for (int l = 0; l < 2; ++l) gload_lds16(srcB[h][l] + ko, &lds[base + dstoff[l]]);
  };

  // ---- fragment ds_read offsets (shorts, within half-block, swizzled) ----
  int aoff[2][2], boff[4][2];
#pragma unroll
  for (int i = 0; i < 2; ++i)
#pragma unroll
    for (int k = 0; k < 2; ++k) {
      int b = (qm * 32 + i * 16 + fr) * 128 + k * 64 + klo * 16;
      b ^= ((b >> 9) & 1) << 5;
      aoff[i][k] = b >> 1;
    }
#pragma unroll
  for (int j = 0; j < 4; ++j)
#pragma unroll
    for (int k = 0; k < 2; ++k) {
      int b = (qn * 64 + j * 16 + fr) * 128 + k * 64 + klo * 16;
      b ^= ((b >> 9) & 1) << 5;
      boff[j][k] = b >> 1;
    }

  f32x4 acc[4][8];
#pragma unroll
  for (int mi = 0; mi < 4; ++mi)
#pragma unroll
    for (int nj = 0; nj < 8; ++nj) acc[mi][nj] = (f32x4){0.f, 0.f, 0.f, 0.f};
  short8 fa[2][2][2], fb[4][2];

  constexpr int NKT = KDIM / 64;
  // prologue: tile0 all halves + B0(1), A1(1)  (order matters for vmcnt(4))
  stB(0, 0, 0); stA(0, 1, 0); stB(0, 1, 0); stA(0, 0, 0);
  stB(32768, 0, 1); stA(32768, 1, 1);
  VM4();
  __builtin_amdgcn_s_barrier();
  __builtin_amdgcn_sched_barrier(0);

  for (int t = 0; t < NKT; ++t) {
    const int d = (t & 1) * 32768;
    const int dn = 32768 - d;
    // q1 (M0,N0): read A0,B0; stage B1(t+1)@dn
    LDA(0, d); LDB(0, d);
    if (t + 1 < NKT) stB(dn, 1, t + 1);
    PHASE_SYNC();
    MFMA_QUAD(0, 0);
    // q2 (M1,N0): read A1; stage A0(t+1)@dn
    LDA(1, d);
    if (t + 1 < NKT) stA(dn, 0, t + 1);
    PHASE_SYNC();
    MFMA_QUAD(1, 0);
    // q3 (M1,N1): read B1; stage B0(t+2)@d
    LDB(1, d);
    if (t + 2 < NKT) stB(d, 0, t + 2);
    PHASE_SYNC();
    MFMA_QUAD(1, 1);
    // q4 (M0,N1): stage A1(t+2)@d; vmcnt(4) once per K-tile
    if (t + 2 < NKT) stA(d, 1, t + 2);
    VM4();
    PHASE_SYNC();
    MFMA_QUAD(0, 1);
  }

  // ---- epilogue: scatter rows to token-indexed buffer ----
  const int fq = lane >> 4;
#pragma unroll
  for (int mi = 0; mi < 4; ++mi) {
    const int rbase = mbase + (mi >> 1) * 128 + qm * 32 + (mi & 1) * 16 + fq * 4;
    int tok[4];
#pragma unroll
    for (int r = 0; r < 4; ++r) tok[r] = sorted[rbase + r];
#pragma unroll
    for (int nj = 0; nj < 8; ++nj) {
      const int col = n0 + (nj >> 2) * 128 + qn * 64 + (nj & 3) * 16 + fr;
      const float bv = bias[(size_t)expert * NDIM + col];
#pragma unroll
      for (int r = 0; r < 4; ++r) {
        if (tok[r] < 0) continue;           // pad row
        float v = acc[mi][nj][r] + bv;
        if (MODE == 0) {
          ((unsigned short*)Cout)[(size_t)tok[r] * NDIM + col] = f2bf(fmaxf(v, 0.f));
        } else {
          ((float*)Cout)[(size_t)tok[r] * NDIM + col] = v;
        }
      }
    }
  }
}

extern "C" void kernel_launch(void* const* d_in, const int* in_sizes, int n_in,
                              void* d_out, int out_size, void* d_ws, size_t ws_size,
                              hipStream_t stream) {
  const float* x  = (const float*)d_in[0];
  const float* Wr = (const float*)d_in[1];
  const float* br = (const float*)d_in[2];
  const float* W1 = (const float*)d_in[3];
  const float* b1 = (const float*)d_in[4];
  const float* W2 = (const float*)d_in[5];
  const float* b2 = (const float*)d_in[6];

  float* out_y      = (float*)d_out;                      // [N,O]
  float* out_probs  = out_y + (size_t)NTOK * OUTD;        // [N,E]
  float* out_counts = out_probs + (size_t)NTOK * NEXP;    // [E]

  char* ws = (char*)d_ws;
  unsigned short* xb   = (unsigned short*)(ws);                                  // 16 MB
  unsigned short* w1t  = (unsigned short*)(ws + 16777216ULL);                    // 32 MB
  unsigned short* w2t  = (unsigned short*)(ws + 50331648ULL);                    // 32 MB
  unsigned short* hbuf = (unsigned short*)(ws + 83886080ULL);                    // 32 MB (token-indexed)
  char* p = ws + 117440512ULL;
  int* routes   = (int*)p; p += 32768;
  int* sorted   = (int*)p; p += (NTOK + NEXP * BM) * 4;   // 40960 B
  int* cursor   = (int*)p; p += 256;
  int* pad_off  = (int*)p; p += 256;
  int2* tt      = (int2*)p;

  hipMemsetAsync(sorted, 0xFF, (NTOK + NEXP * BM) * sizeof(int), stream);
  hipMemsetAsync(cursor, 0, 256, stream);

  transpose_convert_kernel<<<dim3(HID / 64, DIN / 64, NEXP), 256, 0, stream>>>(W1, w1t, DIN, HID);
  transpose_convert_kernel<<<dim3(OUTD / 64, HID / 64, NEXP), 256, 0, stream>>>(W2, w2t, HID, OUTD);
  fused_router_kernel<<<NTOK / 4, 256, 0, stream>>>(x, Wr, br, xb, out_probs, routes);
  hist_scan_kernel<<<1, 256, 0, stream>>>(routes, pad_off, tt, out_counts);
  build_kernel<<<NTOK / 256, 256, 0, stream>>>(routes, pad_off, cursor, sorted);
  gemm_moe<DIN, 0, HID / 256><<<(HID / 256) * MAXT, 512, 0, stream>>>(
      xb, w1t, b1, sorted, tt, hbuf, HID);
  gemm_moe<HID, 1, OUTD / 256><<<(OUTD / 256) * MAXT, 512, 0, stream>>>(
      hbuf, w2t, b2, sorted, tt, out_y, OUTD);
}

// Round 11
// 202.516 us; speedup vs baseline: 1.4182x; 1.0483x over previous
//
#include <hip/hip_runtime.h>
#include <hip/hip_bf16.h>

#define NTOK 8192
#define DIN  1024
#define HID  2048
#define OUTD 1024
#define NEXP 8
#define BM 256
#define MAXT (NTOK / BM + NEXP)   // 40 M-tiles max

typedef short short8 __attribute__((ext_vector_type(8)));
typedef float f32x4 __attribute__((ext_vector_type(4)));

static __device__ __forceinline__ unsigned short f2bf(float f) {
  union { __hip_bfloat16 b; unsigned short u; } cv;
  cv.b = __float2bfloat16(f);
  return cv.u;
}

static __device__ __forceinline__ void gload_lds16(const void* g, void* l) {
  __builtin_amdgcn_global_load_lds(
      (const __attribute__((address_space(1))) void*)g,
      (__attribute__((address_space(3))) void*)l, 16, 0, 0);
}

// ---------------- prep: W [E][R][C] fp32 -> WT [E][C][R] bf16 ----------------
__global__ __launch_bounds__(256) void transpose_convert_kernel(
    const float* __restrict__ W, unsigned short* __restrict__ WT, int R, int C) {
  __shared__ float tile[64][65];
  const int e = blockIdx.z;
  const int c0 = blockIdx.x * 64, r0 = blockIdx.y * 64;
  const int lr = threadIdx.x >> 4;    // 0..15
  const int fc = threadIdx.x & 15;    // float4 column
  const float* Wp = W + ((size_t)e * R + r0) * C + c0;
#pragma unroll
  for (int i = 0; i < 4; ++i) {
    int r = lr + i * 16;
    float4 v = *(const float4*)(Wp + (size_t)r * C + fc * 4);
    tile[r][fc * 4 + 0] = v.x; tile[r][fc * 4 + 1] = v.y;
    tile[r][fc * 4 + 2] = v.z; tile[r][fc * 4 + 3] = v.w;
  }
  __syncthreads();
  unsigned short* Op = WT + ((size_t)e * C + c0) * R + r0;
#pragma unroll
  for (int i = 0; i < 4; ++i) {
    int cc = lr + i * 16;             // output row = source col
    int rb = fc * 4;                  // 4 source rows
    ushort4 o = { f2bf(tile[rb + 0][cc]), f2bf(tile[rb + 1][cc]),
                  f2bf(tile[rb + 2][cc]), f2bf(tile[rb + 3][cc]) };
    *(ushort4*)(Op + (size_t)cc * R + rb) = o;
  }
}

// ---------------- fused: x fp32 -> bf16  +  router (fp32, NO atomics) ------
__global__ __launch_bounds__(256) void fused_router_kernel(
    const float* __restrict__ x, const float* __restrict__ Wr,
    const float* __restrict__ br, unsigned short* __restrict__ xb,
    float* __restrict__ probs_out, int* __restrict__ routes) {
  __shared__ float WrL[NEXP][DIN];   // transposed router weights, 32 KB
  const int tid = threadIdx.x;
#pragma unroll
  for (int rr = 0; rr < 4; ++rr) {
    int row = tid * 4 + rr;
    float4 w0 = *(const float4*)(Wr + (size_t)row * NEXP);
    float4 w1 = *(const float4*)(Wr + (size_t)row * NEXP + 4);
    WrL[0][row] = w0.x; WrL[1][row] = w0.y; WrL[2][row] = w0.z; WrL[3][row] = w0.w;
    WrL[4][row] = w1.x; WrL[5][row] = w1.y; WrL[6][row] = w1.z; WrL[7][row] = w1.w;
  }
  __syncthreads();

  const int lane = tid & 63;
  const int n = blockIdx.x * 4 + (tid >> 6);
  const float4* xr = (const float4*)(x + (size_t)n * DIN);
  ushort4* xo = (ushort4*)(xb + (size_t)n * DIN);
  float acc[NEXP];
#pragma unroll
  for (int e = 0; e < NEXP; ++e) acc[e] = 0.f;
#pragma unroll
  for (int j = 0; j < 4; ++j) {
    int idx = j * 64 + lane;            // coalesced: 64 consecutive float4
    float4 xv = xr[idx];
    ushort4 o = { f2bf(xv.x), f2bf(xv.y), f2bf(xv.z), f2bf(xv.w) };
    xo[idx] = o;
    int r0 = idx * 4;
#pragma unroll
    for (int e = 0; e < NEXP; ++e) {
      float4 wv = *(const float4*)&WrL[e][r0];
      acc[e] += xv.x * wv.x + xv.y * wv.y + xv.z * wv.z + xv.w * wv.w;
    }
  }
#pragma unroll
  for (int m = 1; m < 64; m <<= 1)
#pragma unroll
    for (int e = 0; e < NEXP; ++e) acc[e] += __shfl_xor(acc[e], m);

  if (lane == 0) {
    float lg[NEXP], p[NEXP];
    float mx = -1e30f;
#pragma unroll
    for (int e = 0; e < NEXP; ++e) { lg[e] = acc[e] + br[e]; mx = fmaxf(mx, lg[e]); }
    float s = 0.f;
#pragma unroll
    for (int e = 0; e < NEXP; ++e) { p[e] = expf(lg[e] - mx); s += p[e]; }
    float inv = 1.f / s;
    int best = 0; float bp = -1.f;
#pragma unroll
    for (int e = 0; e < NEXP; ++e) {
      p[e] *= inv;
      probs_out[(size_t)n * NEXP + e] = p[e];
      if (p[e] > bp) { bp = p[e]; best = e; }   // strict > : first-index tie-break
    }
    routes[n] = best;
  }
}

// ---------------- histogram + scan (single block, no atomics) ----------------
__global__ __launch_bounds__(256) void hist_scan_kernel(
    const int* __restrict__ routes, int* __restrict__ pad_off,
    int2* __restrict__ tile_table, float* __restrict__ counts_out) {
  __shared__ int wsum[4][NEXP];
  const int tid = threadIdx.x;
  const int lane = tid & 63, w = tid >> 6;
  int cnt[NEXP];
#pragma unroll
  for (int e = 0; e < NEXP; ++e) cnt[e] = 0;
#pragma unroll
  for (int j = 0; j < 8; ++j) {
    int4 r4 = ((const int4*)routes)[tid + 256 * j];
    int rr[4] = {r4.x, r4.y, r4.z, r4.w};
#pragma unroll
    for (int i = 0; i < 4; ++i)
#pragma unroll
      for (int e = 0; e < NEXP; ++e) cnt[e] += (rr[i] == e);  // no runtime idx -> regs
  }
#pragma unroll
  for (int m = 1; m < 64; m <<= 1)
#pragma unroll
    for (int e = 0; e < NEXP; ++e) cnt[e] += __shfl_xor(cnt[e], m);
  if (lane == 0)
#pragma unroll
    for (int e = 0; e < NEXP; ++e) wsum[w][e] = cnt[e];
  __syncthreads();
  if (tid == 0) {
    int off = 0, t = 0;
    for (int e = 0; e < NEXP; ++e) {
      int c = wsum[0][e] + wsum[1][e] + wsum[2][e] + wsum[3][e];
      pad_off[e] = off;
      counts_out[e] = (float)c;
      int tiles = (c + BM - 1) / BM;
      for (int i = 0; i < tiles; ++i) { tile_table[t] = make_int2(e, off + i * BM); ++t; }
      off += tiles * BM;
    }
    for (; t < MAXT; ++t) tile_table[t] = make_int2(-1, 0);
  }
}

// ---------------- build sorted token list (wave-aggregated atomics) ---------
__global__ void build_kernel(const int* __restrict__ routes,
                             const int* __restrict__ pad_off,
                             int* __restrict__ cursor,
                             int* __restrict__ sorted) {
  const int n = blockIdx.x * 256 + threadIdx.x;
  const int lane = threadIdx.x & 63;
  const int e = routes[n];
#pragma unroll
  for (int ex = 0; ex < NEXP; ++ex) {
    unsigned long long m = __ballot(e == ex);
    if (e == ex) {
      int leader = __ffsll(m) - 1;
      int rank = __popcll(m & ((1ull << lane) - 1ull));
      int b = 0;
      if (rank == 0) b = atomicAdd(&cursor[ex], (int)__popcll(m));
      b = __shfl(b, leader);
      sorted[pad_off[ex] + b + rank] = n;
    }
  }
}

// ============ grouped GEMM: m201 8-phase 256x256, BK=64, ONE barrier/phase ==
// 8 waves, wave grid 4M x 2N PER QUADRANT: each phase computes one 128x128
// C-quadrant (Mh,Nh). LDS = 2 dbuf x [A0|A1|B0|B1] x 16KB = 128 KB; tile t in
// dbuf t&1. Phase p (one raw s_barrier each): [ds_read frags(p); stage;
// barrier; lgkmcnt(0); MFMA(p)] -- ds_reads issue in the same barrier interval
// as MFMA(p-1). Stage plan per K-tile t (half-disjoint, ledger-verified):
// q1->B1(t+1)@dn, q2->A0(t+1)@dn, q3->B0(t+2)@d, q4->A1(t+2)@d. vmcnt(4) at
// q4 completes through A0(t+1) (12-deep FIFO).
// LDS swizzle (G4 fix for 128B rows read as b128): 16B-chunk index ^= row&7,
// i.e. byte ^= ((row&7)<<4). Applied on BOTH the pre-swizzled gload source
// (csw = (c ^ row&7)*8, linear LDS dest) and the ds_read address (rule #21).
// Granule bits become {klo0^fr0, klo1^fr1, k^fr2} -> uniform 8 lanes/granule
// = wave-b128 bank floor (was 16-way same-bank before).
// MODE 0: A = xb gathered, out = relu(acc+b1) -> bf16 hbuf[token][NDIM]
// MODE 1: A = hbuf gathered, out = acc+b2     -> fp32 out[token][NDIM]
#define PHASE_SYNC() do { \
    __builtin_amdgcn_sched_barrier(0); \
    __builtin_amdgcn_s_barrier(); \
    __builtin_amdgcn_sched_barrier(0); \
    asm volatile("s_waitcnt lgkmcnt(0)" ::: "memory"); \
    __builtin_amdgcn_sched_barrier(0); } while (0)
#define VM4()  asm volatile("s_waitcnt vmcnt(4)" ::: "memory")

#define LDA(MH, D) \
  _Pragma("unroll") for (int i_ = 0; i_ < 2; ++i_) \
  _Pragma("unroll") for (int k_ = 0; k_ < 2; ++k_) \
    fa[MH][i_][k_] = *(const short8*)&lds[(D) + (MH) * 8192 + aoff[i_][k_]];
#define LDB(NH, D) \
  _Pragma("unroll") for (int j_ = 0; j_ < 4; ++j_) \
  _Pragma("unroll") for (int k_ = 0; k_ < 2; ++k_) \
    fb[j_][k_] = *(const short8*)&lds[(D) + 16384 + (NH) * 8192 + boff[j_][k_]];
#define MFMA_QUAD(MH, NH) do { __builtin_amdgcn_s_setprio(1); \
  _Pragma("unroll") for (int i_ = 0; i_ < 2; ++i_) \
  _Pragma("unroll") for (int j_ = 0; j_ < 4; ++j_) \
  _Pragma("unroll") for (int k_ = 0; k_ < 2; ++k_) \
    acc[(MH) * 2 + i_][(NH) * 4 + j_] = __builtin_amdgcn_mfma_f32_16x16x32_bf16( \
        fa[MH][i_][k_], fb[j_][k_], acc[(MH) * 2 + i_][(NH) * 4 + j_], 0, 0, 0); \
  __builtin_amdgcn_s_setprio(0); } while (0)

template <int KDIM, int MODE, int NB>
__global__ __launch_bounds__(512, 2) void gemm_moe(
    const unsigned short* __restrict__ A, const unsigned short* __restrict__ WT,
    const float* __restrict__ bias, const int* __restrict__ sorted,
    const int2* __restrict__ tile_table, void* __restrict__ Cout, int NDIM) {
  __shared__ short lds[65536];   // 128 KB

  // T1 bijective XCD swizzle (nwg % 8 == 0)
  const int nwg = NB * MAXT;
  const int bid = blockIdx.x;
  const int swz = (bid & 7) * (nwg >> 3) + (bid >> 3);
  const int2 tt = tile_table[swz / NB];
  if (tt.x < 0) return;
  const int expert = tt.x, mbase = tt.y;
  const int n0 = (swz % NB) * 256;
  const int tid = threadIdx.x, lane = tid & 63, w = tid >> 6;
  const int qm = w >> 1, qn = w & 1;       // wave grid 4M x 2N within a quadrant
  const int fr = lane & 15, klo = lane >> 4;

  // ---- staging descriptors: 2 x 16B chunks per thread per half-tile ----
  const short* srcA[2][2];   // [half][load]
  const short* srcB[2][2];
  int dstoff[2];
#pragma unroll
  for (int l = 0; l < 2; ++l) {
    const int ch = l * 512 + tid;                       // physical chunk (row-major)
    const int row = ch >> 3;                            // 128 rows x 8 chunks
    const int csw = ((ch & 7) ^ (row & 7)) * 8;         // inverse-swizzled source
    dstoff[l] = ch * 8;                                 // linear LDS dest
#pragma unroll
    for (int h = 0; h < 2; ++h) {
      int tok = sorted[mbase + h * 128 + row];
      if (tok < 0) tok = 0;                             // pad: dropped at store
      srcA[h][l] = (const short*)A + (size_t)tok * KDIM + csw;
      srcB[h][l] = (const short*)WT + ((size_t)expert * NDIM + n0 + h * 128 + row) * KDIM + csw;
    }
  }
  auto stA = [&](int doff, int h, int kt) {
    const int base = doff + h * 8192, ko = kt * 64;
#pragma unroll
    for (int l = 0; l < 2; ++l) gload_lds16(srcA[h][l] + ko, &lds[base + dstoff[l]]);
  };
  auto stB = [&](int doff, int h, int kt) {
    const int base = doff + 16384 + h * 8192, ko = kt * 64;
#pragma unroll
    for (int l = 0; l < 2; ++l) gload_lds16(srcB[h][l] + ko, &lds[base + dstoff[l]]);
  };

  // ---- fragment ds_read offsets (shorts, within half-block, swizzled) ----
  const int rsw = (fr & 7) << 4;            // row&7 == fr&7 (bases are x8)
  int aoff[2][2], boff[4][2];
#pragma unroll
  for (int i = 0; i < 2; ++i)
#pragma unroll
    for (int k = 0; k < 2; ++k) {
      int b = (qm * 32 + i * 16 + fr) * 128 + k * 64 + klo * 16;
      aoff[i][k] = (b ^ rsw) >> 1;
    }
#pragma unroll
  for (int j = 0; j < 4; ++j)
#pragma unroll
    for (int k = 0; k < 2; ++k) {
      int b = (qn * 64 + j * 16 + fr) * 128 + k * 64 + klo * 16;
      boff[j][k] = (b ^ rsw) >> 1;
    }

  f32x4 acc[4][8];
#pragma unroll
  for (int mi = 0; mi < 4; ++mi)
#pragma unroll
    for (int nj = 0; nj < 8; ++nj) acc[mi][nj] = (f32x4){0.f, 0.f, 0.f, 0.f};
  short8 fa[2][2][2], fb[4][2];

  constexpr int NKT = KDIM / 64;
  // prologue: tile0 all halves + B0(1), A1(1)  (order matters for vmcnt(4))
  stB(0, 0, 0); stA(0, 1, 0); stB(0, 1, 0); stA(0, 0, 0);
  stB(32768, 0, 1); stA(32768, 1, 1);
  VM4();
  __builtin_amdgcn_s_barrier();
  __builtin_amdgcn_sched_barrier(0);

  for (int t = 0; t < NKT; ++t) {
    const int d = (t & 1) * 32768;
    const int dn = 32768 - d;
    // q1 (M0,N0): read A0,B0; stage B1(t+1)@dn
    LDA(0, d); LDB(0, d);
    if (t + 1 < NKT) stB(dn, 1, t + 1);
    PHASE_SYNC();
    MFMA_QUAD(0, 0);
    // q2 (M1,N0): read A1; stage A0(t+1)@dn
    LDA(1, d);
    if (t + 1 < NKT) stA(dn, 0, t + 1);
    PHASE_SYNC();
    MFMA_QUAD(1, 0);
    // q3 (M1,N1): read B1; stage B0(t+2)@d
    LDB(1, d);
    if (t + 2 < NKT) stB(d, 0, t + 2);
    PHASE_SYNC();
    MFMA_QUAD(1, 1);
    // q4 (M0,N1): stage A1(t+2)@d; vmcnt(4) once per K-tile
    if (t + 2 < NKT) stA(d, 1, t + 2);
    VM4();
    PHASE_SYNC();
    MFMA_QUAD(0, 1);
  }

  // ---- epilogue: scatter rows to token-indexed buffer ----
  const int fq = lane >> 4;
#pragma unroll
  for (int mi = 0; mi < 4; ++mi) {
    const int rbase = mbase + (mi >> 1) * 128 + qm * 32 + (mi & 1) * 16 + fq * 4;
    int tok[4];
#pragma unroll
    for (int r = 0; r < 4; ++r) tok[r] = sorted[rbase + r];
#pragma unroll
    for (int nj = 0; nj < 8; ++nj) {
      const int col = n0 + (nj >> 2) * 128 + qn * 64 + (nj & 3) * 16 + fr;
      const float bv = bias[(size_t)expert * NDIM + col];
#pragma unroll
      for (int r = 0; r < 4; ++r) {
        if (tok[r] < 0) continue;           // pad row
        float v = acc[mi][nj][r] + bv;
        if (MODE == 0) {
          ((unsigned short*)Cout)[(size_t)tok[r] * NDIM + col] = f2bf(fmaxf(v, 0.f));
        } else {
          ((float*)Cout)[(size_t)tok[r] * NDIM + col] = v;
        }
      }
    }
  }
}

extern "C" void kernel_launch(void* const* d_in, const int* in_sizes, int n_in,
                              void* d_out, int out_size, void* d_ws, size_t ws_size,
                              hipStream_t stream) {
  const float* x  = (const float*)d_in[0];
  const float* Wr = (const float*)d_in[1];
  const float* br = (const float*)d_in[2];
  const float* W1 = (const float*)d_in[3];
  const float* b1 = (const float*)d_in[4];
  const float* W2 = (const float*)d_in[5];
  const float* b2 = (const float*)d_in[6];

  float* out_y      = (float*)d_out;                      // [N,O]
  float* out_probs  = out_y + (size_t)NTOK * OUTD;        // [N,E]
  float* out_counts = out_probs + (size_t)NTOK * NEXP;    // [E]

  char* ws = (char*)d_ws;
  unsigned short* xb   = (unsigned short*)(ws);                                  // 16 MB
  unsigned short* w1t  = (unsigned short*)(ws + 16777216ULL);                    // 32 MB
  unsigned short* w2t  = (unsigned short*)(ws + 50331648ULL);                    // 32 MB
  unsigned short* hbuf = (unsigned short*)(ws + 83886080ULL);                    // 32 MB (token-indexed)
  char* p = ws + 117440512ULL;
  int* routes   = (int*)p; p += 32768;
  int* sorted   = (int*)p; p += (NTOK + NEXP * BM) * 4;   // 40960 B
  int* cursor   = (int*)p; p += 256;
  int* pad_off  = (int*)p; p += 256;
  int2* tt      = (int2*)p;

  hipMemsetAsync(sorted, 0xFF, (NTOK + NEXP * BM) * sizeof(int), stream);
  hipMemsetAsync(cursor, 0, 256, stream);

  transpose_convert_kernel<<<dim3(HID / 64, DIN / 64, NEXP), 256, 0, stream>>>(W1, w1t, DIN, HID);
  transpose_convert_kernel<<<dim3(OUTD / 64, HID / 64, NEXP), 256, 0, stream>>>(W2, w2t, HID, OUTD);
  fused_router_kernel<<<NTOK / 4, 256, 0, stream>>>(x, Wr, br, xb, out_probs, routes);
  hist_scan_kernel<<<1, 256, 0, stream>>>(routes, pad_off, tt, out_counts);
  build_kernel<<<NTOK / 256, 256, 0, stream>>>(routes, pad_off, cursor, sorted);
  gemm_moe<DIN, 0, HID / 256><<<(HID / 256) * MAXT, 512, 0, stream>>>(
      xb, w1t, b1, sorted, tt, hbuf, HID);
  gemm_moe<HID, 1, OUTD / 256><<<(OUTD / 256) * MAXT, 512, 0, stream>>>(
      hbuf, w2t, b2, sorted, tt, out_y, OUTD);
}

// Round 12
// 202.130 us; speedup vs baseline: 1.4209x; 1.0019x over previous
//
#include <hip/hip_runtime.h>
#include <hip/hip_bf16.h>

#define NTOK 8192
#define DIN  1024
#define HID  2048
#define OUTD 1024
#define NEXP 8
#define BM 128
#define MAXT (NTOK / BM + NEXP)   // 72 M-tiles max

typedef short short8 __attribute__((ext_vector_type(8)));
typedef float f32x4 __attribute__((ext_vector_type(4)));

static __device__ __forceinline__ unsigned short f2bf(float f) {
  union { __hip_bfloat16 b; unsigned short u; } cv;
  cv.b = __float2bfloat16(f);
  return cv.u;
}

static __device__ __forceinline__ void gload_lds16(const void* g, void* l) {
  __builtin_amdgcn_global_load_lds(
      (const __attribute__((address_space(1))) void*)g,
      (__attribute__((address_space(3))) void*)l, 16, 0, 0);
}

// ---------------- prep: W [E][R][C] fp32 -> WT [E][C][R] bf16 ----------------
__global__ __launch_bounds__(256) void transpose_convert_kernel(
    const float* __restrict__ W, unsigned short* __restrict__ WT, int R, int C) {
  __shared__ float tile[64][65];
  const int e = blockIdx.z;
  const int c0 = blockIdx.x * 64, r0 = blockIdx.y * 64;
  const int lr = threadIdx.x >> 4;    // 0..15
  const int fc = threadIdx.x & 15;    // float4 column
  const float* Wp = W + ((size_t)e * R + r0) * C + c0;
#pragma unroll
  for (int i = 0; i < 4; ++i) {
    int r = lr + i * 16;
    float4 v = *(const float4*)(Wp + (size_t)r * C + fc * 4);
    tile[r][fc * 4 + 0] = v.x; tile[r][fc * 4 + 1] = v.y;
    tile[r][fc * 4 + 2] = v.z; tile[r][fc * 4 + 3] = v.w;
  }
  __syncthreads();
  unsigned short* Op = WT + ((size_t)e * C + c0) * R + r0;
#pragma unroll
  for (int i = 0; i < 4; ++i) {
    int cc = lr + i * 16;             // output row = source col
    int rb = fc * 4;                  // 4 source rows
    ushort4 o = { f2bf(tile[rb + 0][cc]), f2bf(tile[rb + 1][cc]),
                  f2bf(tile[rb + 2][cc]), f2bf(tile[rb + 3][cc]) };
    *(ushort4*)(Op + (size_t)cc * R + rb) = o;
  }
}

// ---------------- fused: x fp32 -> bf16  +  router (fp32, NO atomics) ------
__global__ __launch_bounds__(256) void fused_router_kernel(
    const float* __restrict__ x, const float* __restrict__ Wr,
    const float* __restrict__ br, unsigned short* __restrict__ xb,
    float* __restrict__ probs_out, int* __restrict__ routes) {
  __shared__ float WrL[NEXP][DIN];   // transposed router weights, 32 KB
  const int tid = threadIdx.x;
#pragma unroll
  for (int rr = 0; rr < 4; ++rr) {
    int row = tid * 4 + rr;
    float4 w0 = *(const float4*)(Wr + (size_t)row * NEXP);
    float4 w1 = *(const float4*)(Wr + (size_t)row * NEXP + 4);
    WrL[0][row] = w0.x; WrL[1][row] = w0.y; WrL[2][row] = w0.z; WrL[3][row] = w0.w;
    WrL[4][row] = w1.x; WrL[5][row] = w1.y; WrL[6][row] = w1.z; WrL[7][row] = w1.w;
  }
  __syncthreads();

  const int lane = tid & 63;
  const int n = blockIdx.x * 4 + (tid >> 6);
  const float4* xr = (const float4*)(x + (size_t)n * DIN);
  ushort4* xo = (ushort4*)(xb + (size_t)n * DIN);
  float acc[NEXP];
#pragma unroll
  for (int e = 0; e < NEXP; ++e) acc[e] = 0.f;
#pragma unroll
  for (int j = 0; j < 4; ++j) {
    int idx = j * 64 + lane;            // coalesced: 64 consecutive float4
    float4 xv = xr[idx];
    ushort4 o = { f2bf(xv.x), f2bf(xv.y), f2bf(xv.z), f2bf(xv.w) };
    xo[idx] = o;
    int r0 = idx * 4;
#pragma unroll
    for (int e = 0; e < NEXP; ++e) {
      float4 wv = *(const float4*)&WrL[e][r0];
      acc[e] += xv.x * wv.x + xv.y * wv.y + xv.z * wv.z + xv.w * wv.w;
    }
  }
#pragma unroll
  for (int m = 1; m < 64; m <<= 1)
#pragma unroll
    for (int e = 0; e < NEXP; ++e) acc[e] += __shfl_xor(acc[e], m);

  if (lane == 0) {
    float lg[NEXP], p[NEXP];
    float mx = -1e30f;
#pragma unroll
    for (int e = 0; e < NEXP; ++e) { lg[e] = acc[e] + br[e]; mx = fmaxf(mx, lg[e]); }
    float s = 0.f;
#pragma unroll
    for (int e = 0; e < NEXP; ++e) { p[e] = expf(lg[e] - mx); s += p[e]; }
    float inv = 1.f / s;
    int best = 0; float bp = -1.f;
#pragma unroll
    for (int e = 0; e < NEXP; ++e) {
      p[e] *= inv;
      probs_out[(size_t)n * NEXP + e] = p[e];
      if (p[e] > bp) { bp = p[e]; best = e; }   // strict > : first-index tie-break
    }
    routes[n] = best;
  }
}

// ---------------- histogram + scan (single block, no atomics) ----------------
__global__ __launch_bounds__(256) void hist_scan_kernel(
    const int* __restrict__ routes, int* __restrict__ pad_off,
    int2* __restrict__ tile_table, float* __restrict__ counts_out) {
  __shared__ int wsum[4][NEXP];
  const int tid = threadIdx.x;
  const int lane = tid & 63, w = tid >> 6;
  int cnt[NEXP];
#pragma unroll
  for (int e = 0; e < NEXP; ++e) cnt[e] = 0;
#pragma unroll
  for (int j = 0; j < 8; ++j) {
    int4 r4 = ((const int4*)routes)[tid + 256 * j];
    int rr[4] = {r4.x, r4.y, r4.z, r4.w};
#pragma unroll
    for (int i = 0; i < 4; ++i)
#pragma unroll
      for (int e = 0; e < NEXP; ++e) cnt[e] += (rr[i] == e);  // no runtime idx -> regs
  }
#pragma unroll
  for (int m = 1; m < 64; m <<= 1)
#pragma unroll
    for (int e = 0; e < NEXP; ++e) cnt[e] += __shfl_xor(cnt[e], m);
  if (lane == 0)
#pragma unroll
    for (int e = 0; e < NEXP; ++e) wsum[w][e] = cnt[e];
  __syncthreads();
  if (tid == 0) {
    int off = 0, t = 0;
    for (int e = 0; e < NEXP; ++e) {
      int c = wsum[0][e] + wsum[1][e] + wsum[2][e] + wsum[3][e];
      pad_off[e] = off;
      counts_out[e] = (float)c;
      int tiles = (c + BM - 1) / BM;
      for (int i = 0; i < tiles; ++i) { tile_table[t] = make_int2(e, off + i * BM); ++t; }
      off += tiles * BM;
    }
    for (; t < MAXT; ++t) tile_table[t] = make_int2(-1, 0);
  }
}

// ---------------- build sorted token list (wave-aggregated atomics) ---------
__global__ void build_kernel(const int* __restrict__ routes,
                             const int* __restrict__ pad_off,
                             int* __restrict__ cursor,
                             int* __restrict__ sorted) {
  const int n = blockIdx.x * 256 + threadIdx.x;
  const int lane = threadIdx.x & 63;
  const int e = routes[n];
#pragma unroll
  for (int ex = 0; ex < NEXP; ++ex) {
    unsigned long long m = __ballot(e == ex);
    if (e == ex) {
      int leader = __ffsll(m) - 1;
      int rank = __popcll(m & ((1ull << lane) - 1ull));
      int b = 0;
      if (rank == 0) b = atomicAdd(&cursor[ex], (int)__popcll(m));
      b = __shfl(b, leader);
      sorted[pad_off[ex] + b + rank] = n;
    }
  }
}

// ===== grouped GEMM: 128x128 tile, BK=64, 4 waves, 4-phase, 2 blocks/CU =====
// Same verified template as R11 but halved tile: quads are 64x64 halves
// (A0/A1 rows, B0/B1 cols); 4 waves as 2M x 2N per quad (wave output 64x64
// across the 4 quads). LDS = 2 dbuf x [A0|A1|B0|B1] x 8KB = 64 KB -> TWO
// blocks/CU: two independent barrier groups interleave, hiding the
// phase-sync stalls that capped R11 at ~15% of the structural floor.
// Phase p: [ds_read frags(p); stage; barrier; lgkmcnt(0); MFMA(p)].
// Stage rotation per K-tile t (ledger identical to R11, re-verified):
// q1->B1(t+1)@dn, q2->A0(t+1)@dn, q3->B0(t+2)@d, q4->A1(t+2)@d; per-wave 2
// vm-instr per stage -> 12 outstanding at q4, vmcnt(4) drains through
// A0(t+1). Swizzle (G4): chunk ^= row&7 on pre-swizzled gload source AND
// byte ^= (fr&7)<<4 on ds_read (row bases x16 => row&7 == fr&7) (rule #21).
// MODE 0: A = xb gathered, out = relu(acc+b1) -> bf16 hbuf[token][NDIM]
// MODE 1: A = hbuf gathered, out = acc+b2     -> fp32 out[token][NDIM]
#define PHASE_SYNC() do { \
    __builtin_amdgcn_sched_barrier(0); \
    __builtin_amdgcn_s_barrier(); \
    __builtin_amdgcn_sched_barrier(0); \
    asm volatile("s_waitcnt lgkmcnt(0)" ::: "memory"); \
    __builtin_amdgcn_sched_barrier(0); } while (0)
#define VM4()  asm volatile("s_waitcnt vmcnt(4)" ::: "memory")

#define LDA(MH, D) \
  _Pragma("unroll") for (int i_ = 0; i_ < 2; ++i_) \
  _Pragma("unroll") for (int k_ = 0; k_ < 2; ++k_) \
    fa[MH][i_][k_] = *(const short8*)&lds[(D) + (MH) * 4096 + aoff[i_][k_]];
#define LDB(NH, D) \
  _Pragma("unroll") for (int j_ = 0; j_ < 2; ++j_) \
  _Pragma("unroll") for (int k_ = 0; k_ < 2; ++k_) \
    fb[j_][k_] = *(const short8*)&lds[(D) + 8192 + (NH) * 4096 + boff[j_][k_]];
#define MFMA_QUAD(MH, NH) do { __builtin_amdgcn_s_setprio(1); \
  _Pragma("unroll") for (int i_ = 0; i_ < 2; ++i_) \
  _Pragma("unroll") for (int j_ = 0; j_ < 2; ++j_) \
  _Pragma("unroll") for (int k_ = 0; k_ < 2; ++k_) \
    acc[(MH) * 2 + i_][(NH) * 2 + j_] = __builtin_amdgcn_mfma_f32_16x16x32_bf16( \
        fa[MH][i_][k_], fb[j_][k_], acc[(MH) * 2 + i_][(NH) * 2 + j_], 0, 0, 0); \
  __builtin_amdgcn_s_setprio(0); } while (0)

template <int KDIM, int MODE, int NB>
__global__ __launch_bounds__(256, 2) void gemm_moe(
    const unsigned short* __restrict__ A, const unsigned short* __restrict__ WT,
    const float* __restrict__ bias, const int* __restrict__ sorted,
    const int2* __restrict__ tile_table, void* __restrict__ Cout, int NDIM) {
  __shared__ short lds[32768];   // 64 KB -> 2 blocks/CU

  // T1 bijective XCD swizzle (nwg % 8 == 0)
  const int nwg = NB * MAXT;
  const int bid = blockIdx.x;
  const int swz = (bid & 7) * (nwg >> 3) + (bid >> 3);
  const int2 tt = tile_table[swz / NB];
  if (tt.x < 0) return;
  const int expert = tt.x, mbase = tt.y;
  const int n0 = (swz % NB) * 128;
  const int tid = threadIdx.x, lane = tid & 63, w = tid >> 6;
  const int qm = w >> 1, qn = w & 1;       // wave grid 2M x 2N within a quadrant
  const int fr = lane & 15, klo = lane >> 4;

  // ---- staging descriptors: 2 x 16B chunks per thread per half-tile ----
  const short* srcA[2][2];   // [half][load]
  const short* srcB[2][2];
  int dstoff[2];
#pragma unroll
  for (int l = 0; l < 2; ++l) {
    const int ch = l * 256 + tid;                       // chunk 0..511 (row-major)
    const int row = ch >> 3;                            // 64 rows x 8 chunks
    const int csw = ((ch & 7) ^ (row & 7)) * 8;         // inverse-swizzled source
    dstoff[l] = ch * 8;                                 // linear LDS dest (shorts)
#pragma unroll
    for (int h = 0; h < 2; ++h) {
      int tok = sorted[mbase + h * 64 + row];
      if (tok < 0) tok = 0;                             // pad: dropped at store
      srcA[h][l] = (const short*)A + (size_t)tok * KDIM + csw;
      srcB[h][l] = (const short*)WT + ((size_t)expert * NDIM + n0 + h * 64 + row) * KDIM + csw;
    }
  }
  auto stA = [&](int doff, int h, int kt) {
    const int base = doff + h * 4096, ko = kt * 64;
#pragma unroll
    for (int l = 0; l < 2; ++l) gload_lds16(srcA[h][l] + ko, &lds[base + dstoff[l]]);
  };
  auto stB = [&](int doff, int h, int kt) {
    const int base = doff + 8192 + h * 4096, ko = kt * 64;
#pragma unroll
    for (int l = 0; l < 2; ++l) gload_lds16(srcB[h][l] + ko, &lds[base + dstoff[l]]);
  };

  // ---- fragment ds_read offsets (shorts, within 8KB half, swizzled) ----
  const int rsw = (fr & 7) << 4;            // row&7 == fr&7 (bases are x16)
  int aoff[2][2], boff[2][2];
#pragma unroll
  for (int i = 0; i < 2; ++i)
#pragma unroll
    for (int k = 0; k < 2; ++k) {
      int b = (qm * 32 + i * 16 + fr) * 128 + k * 64 + klo * 16;
      aoff[i][k] = (b ^ rsw) >> 1;
    }
#pragma unroll
  for (int j = 0; j < 2; ++j)
#pragma unroll
    for (int k = 0; k < 2; ++k) {
      int b = (qn * 32 + j * 16 + fr) * 128 + k * 64 + klo * 16;
      boff[j][k] = (b ^ rsw) >> 1;
    }

  f32x4 acc[4][4];
#pragma unroll
  for (int mi = 0; mi < 4; ++mi)
#pragma unroll
    for (int nj = 0; nj < 4; ++nj) acc[mi][nj] = (f32x4){0.f, 0.f, 0.f, 0.f};
  short8 fa[2][2][2], fb[2][2];

  constexpr int NKT = KDIM / 64;
  // prologue: tile0 all halves + B0(1), A1(1)  (order matters for vmcnt)
  stB(0, 0, 0); stA(0, 1, 0); stB(0, 1, 0); stA(0, 0, 0);
  stB(16384, 0, 1); stA(16384, 1, 1);
  VM4();
  __builtin_amdgcn_s_barrier();
  __builtin_amdgcn_sched_barrier(0);

  for (int t = 0; t < NKT; ++t) {
    const int d = (t & 1) * 16384;
    const int dn = 16384 - d;
    // q1 (M0,N0): read A0,B0; stage B1(t+1)@dn
    LDA(0, d); LDB(0, d);
    if (t + 1 < NKT) stB(dn, 1, t + 1);
    PHASE_SYNC();
    MFMA_QUAD(0, 0);
    // q2 (M1,N0): read A1; stage A0(t+1)@dn
    LDA(1, d);
    if (t + 1 < NKT) stA(dn, 0, t + 1);
    PHASE_SYNC();
    MFMA_QUAD(1, 0);
    // q3 (M1,N1): read B1; stage B0(t+2)@d
    LDB(1, d);
    if (t + 2 < NKT) stB(d, 0, t + 2);
    PHASE_SYNC();
    MFMA_QUAD(1, 1);
    // q4 (M0,N1): stage A1(t+2)@d; vmcnt(4) once per K-tile
    if (t + 2 < NKT) stA(d, 1, t + 2);
    VM4();
    PHASE_SYNC();
    MFMA_QUAD(0, 1);
  }

  // ---- epilogue: scatter rows to token-indexed buffer ----
  const int fq = lane >> 4;
#pragma unroll
  for (int mi = 0; mi < 4; ++mi) {
    const int rbase = mbase + (mi >> 1) * 64 + qm * 32 + (mi & 1) * 16 + fq * 4;
    int tok[4];
#pragma unroll
    for (int r = 0; r < 4; ++r) tok[r] = sorted[rbase + r];
#pragma unroll
    for (int nj = 0; nj < 4; ++nj) {
      const int col = n0 + (nj >> 1) * 64 + qn * 32 + (nj & 1) * 16 + fr;
      const float bv = bias[(size_t)expert * NDIM + col];
#pragma unroll
      for (int r = 0; r < 4; ++r) {
        if (tok[r] < 0) continue;           // pad row
        float v = acc[mi][nj][r] + bv;
        if (MODE == 0) {
          ((unsigned short*)Cout)[(size_t)tok[r] * NDIM + col] = f2bf(fmaxf(v, 0.f));
        } else {
          ((float*)Cout)[(size_t)tok[r] * NDIM + col] = v;
        }
      }
    }
  }
}

extern "C" void kernel_launch(void* const* d_in, const int* in_sizes, int n_in,
                              void* d_out, int out_size, void* d_ws, size_t ws_size,
                              hipStream_t stream) {
  const float* x  = (const float*)d_in[0];
  const float* Wr = (const float*)d_in[1];
  const float* br = (const float*)d_in[2];
  const float* W1 = (const float*)d_in[3];
  const float* b1 = (const float*)d_in[4];
  const float* W2 = (const float*)d_in[5];
  const float* b2 = (const float*)d_in[6];

  float* out_y      = (float*)d_out;                      // [N,O]
  float* out_probs  = out_y + (size_t)NTOK * OUTD;        // [N,E]
  float* out_counts = out_probs + (size_t)NTOK * NEXP;    // [E]

  char* ws = (char*)d_ws;
  unsigned short* xb   = (unsigned short*)(ws);                                  // 16 MB
  unsigned short* w1t  = (unsigned short*)(ws + 16777216ULL);                    // 32 MB
  unsigned short* w2t  = (unsigned short*)(ws + 50331648ULL);                    // 32 MB
  unsigned short* hbuf = (unsigned short*)(ws + 83886080ULL);                    // 32 MB (token-indexed)
  char* p = ws + 117440512ULL;
  int* routes   = (int*)p; p += 32768;
  int* sorted   = (int*)p; p += (NTOK + NEXP * BM) * 4;
  int* cursor   = (int*)p; p += 256;
  int* pad_off  = (int*)p; p += 256;
  int2* tt      = (int2*)p;

  hipMemsetAsync(sorted, 0xFF, (NTOK + NEXP * BM) * sizeof(int), stream);
  hipMemsetAsync(cursor, 0, 256, stream);

  transpose_convert_kernel<<<dim3(HID / 64, DIN / 64, NEXP), 256, 0, stream>>>(W1, w1t, DIN, HID);
  transpose_convert_kernel<<<dim3(OUTD / 64, HID / 64, NEXP), 256, 0, stream>>>(W2, w2t, HID, OUTD);
  fused_router_kernel<<<NTOK / 4, 256, 0, stream>>>(x, Wr, br, xb, out_probs, routes);
  hist_scan_kernel<<<1, 256, 0, stream>>>(routes, pad_off, tt, out_counts);
  build_kernel<<<NTOK / 256, 256, 0, stream>>>(routes, pad_off, cursor, sorted);
  gemm_moe<DIN, 0, HID / 128><<<(HID / 128) * MAXT, 256, 0, stream>>>(
      xb, w1t, b1, sorted, tt, hbuf, HID);
  gemm_moe<HID, 1, OUTD / 128><<<(OUTD / 128) * MAXT, 256, 0, stream>>>(
      hbuf, w2t, b2, sorted, tt, out_y, OUTD);
}